// Round 1
// baseline (9910.883 us; speedup 1.0000x reference)
//
#include <hip/hip_runtime.h>
#include <cstddef>
#include <cstdint>

constexpr int IN_F  = 128;
constexpr int HID_F = 256;
constexpr int EMB_F = 64;

// ---------------- degree / dinv ----------------

__global__ void k_deg_init(int* __restrict__ deg, int n) {
  int i = blockIdx.x * blockDim.x + threadIdx.x;
  if (i < n) deg[i] = 1;  // self loop
}

__global__ void k_deg_accum(const int* __restrict__ dst, int* __restrict__ deg, int e) {
  int i = blockIdx.x * blockDim.x + threadIdx.x;
  if (i < e) atomicAdd(&deg[dst[i]], 1);
}

__global__ void k_dinv(const int* __restrict__ deg, float* __restrict__ dinv, int n) {
  int i = blockIdx.x * blockDim.x + threadIdx.x;
  if (i < n) dinv[i] = rsqrtf((float)deg[i]);  // deg >= 1 always
}

// ---------------- xs = x * dinv[row]  (F=128, float4) ----------------

__global__ void k_scale_x(const float* __restrict__ x, const float* __restrict__ dinv,
                          float* __restrict__ xs, int n4 /* N*32 */) {
  int i = blockIdx.x * blockDim.x + threadIdx.x;
  if (i >= n4) return;
  int row = i >> 5;  // 32 float4 per row
  float s = dinv[row];
  float4 v = reinterpret_cast<const float4*>(x)[i];
  v.x *= s; v.y *= s; v.z *= s; v.w *= s;
  reinterpret_cast<float4*>(xs)[i] = v;
}

// ---------------- edge scatter: agg[dst,:] += t[src,:] ----------------

template<int F>
__global__ void k_scatter(const float* __restrict__ t, float* __restrict__ agg,
                          const int* __restrict__ src, const int* __restrict__ dst,
                          long long total /* E * F/4 */) {
  constexpr int LPE = F / 4;  // lanes per edge (pow2 -> shifts)
  long long i = (long long)blockIdx.x * blockDim.x + threadIdx.x;
  if (i >= total) return;
  int e = (int)(i / LPE);
  int l = (int)(i - (long long)e * LPE);
  int s = src[e], d = dst[e];
  float4 v = *reinterpret_cast<const float4*>(t + (size_t)s * F + (size_t)l * 4);
  float* p = agg + (size_t)d * F + (size_t)l * 4;
  atomicAdd(p + 0, v.x);
  atomicAdd(p + 1, v.y);
  atomicAdd(p + 2, v.z);
  atomicAdd(p + 3, v.w);
}

// ---------------- tiled fp32 GEMM: C[M,F] = op(A[M,K]) @ B[K,F] ----------------
// FLAGS bit0: scale A rows by dinv;  bit1: scale C rows by dinv;  bit2: +bias, relu

template<int FLAGS>
__global__ __launch_bounds__(256) void k_gemm(
    const float* __restrict__ A, const float* __restrict__ B, float* __restrict__ C,
    int M, int K, int F,
    const float* __restrict__ dinv, const float* __restrict__ bias) {
  __shared__ float As[64][68];  // transposed: As[k][m], pad keeps 16B alignment
  __shared__ float Bs[64][68];
  const int tid = threadIdx.x;
  const int tx = tid & 15, ty = tid >> 4;
  const int bm = blockIdx.x * 64, bn = blockIdx.y * 64;
  float acc[4][4] = {};
  const int lrow = tid >> 4;            // 0..15
  const int lcol = (tid & 15) * 4;      // 0..60

  for (int k0 = 0; k0 < K; k0 += 64) {
#pragma unroll
    for (int r = 0; r < 4; ++r) {
      int row = lrow + r * 16;          // 0..63
      int grow = bm + row;
      float4 v = make_float4(0.f, 0.f, 0.f, 0.f);
      if (grow < M) {
        v = *reinterpret_cast<const float4*>(A + (size_t)grow * K + k0 + lcol);
        if (FLAGS & 1) { float s = dinv[grow]; v.x *= s; v.y *= s; v.z *= s; v.w *= s; }
      }
      As[lcol + 0][row] = v.x;
      As[lcol + 1][row] = v.y;
      As[lcol + 2][row] = v.z;
      As[lcol + 3][row] = v.w;
      float4 w = *reinterpret_cast<const float4*>(B + (size_t)(k0 + row) * F + bn + lcol);
      *reinterpret_cast<float4*>(&Bs[row][lcol]) = w;
    }
    __syncthreads();
#pragma unroll
    for (int kk = 0; kk < 64; ++kk) {
      float4 av = *reinterpret_cast<const float4*>(&As[kk][ty * 4]);
      float4 bv = *reinterpret_cast<const float4*>(&Bs[kk][tx * 4]);
      float a[4] = {av.x, av.y, av.z, av.w};
      float b[4] = {bv.x, bv.y, bv.z, bv.w};
#pragma unroll
      for (int i = 0; i < 4; ++i)
#pragma unroll
        for (int j = 0; j < 4; ++j)
          acc[i][j] = fmaf(a[i], b[j], acc[i][j]);
    }
    __syncthreads();
  }

#pragma unroll
  for (int i = 0; i < 4; ++i) {
    int grow = bm + ty * 4 + i;
    if (grow >= M) continue;
    float s = (FLAGS & 2) ? dinv[grow] : 1.0f;
#pragma unroll
    for (int j = 0; j < 4; ++j) {
      int gcol = bn + tx * 4 + j;
      float v = acc[i][j] * s;
      if (FLAGS & 4) v = fmaxf(v + bias[gcol], 0.f);
      C[(size_t)grow * F + gcol] = v;
    }
  }
}

// ---------------- h = relu(agg*dinv + bias), F=256 in-place ----------------

__global__ void k_bias_relu(float* __restrict__ h, const float* __restrict__ dinv,
                            const float* __restrict__ bias, int n4 /* N*64 */) {
  int i = blockIdx.x * blockDim.x + threadIdx.x;
  if (i >= n4) return;
  int row = i >> 6;            // 64 float4 per row
  int c = (i & 63) * 4;
  float s = dinv[row];
  float4 v = reinterpret_cast<float4*>(h)[i];
  v.x = fmaxf(fmaf(v.x, s, bias[c + 0]), 0.f);
  v.y = fmaxf(fmaf(v.y, s, bias[c + 1]), 0.f);
  v.z = fmaxf(fmaf(v.z, s, bias[c + 2]), 0.f);
  v.w = fmaxf(fmaf(v.w, s, bias[c + 3]), 0.f);
  reinterpret_cast<float4*>(h)[i] = v;
}

// ---------------- final: out = normalize(agg*dinv + b3), F=64, one wave/row ----------------

__global__ void k_final(float* __restrict__ out, const float* __restrict__ dinv,
                        const float* __restrict__ b3, int n) {
  int gid = blockIdx.x * blockDim.x + threadIdx.x;
  int row = gid >> 6;
  int lane = gid & 63;
  if (row >= n) return;
  size_t idx = (size_t)row * 64 + lane;
  float v = fmaf(out[idx], dinv[row], b3[lane]);
  float ss = v * v;
#pragma unroll
  for (int off = 32; off > 0; off >>= 1) ss += __shfl_xor(ss, off);
  float nrm = sqrtf(ss);
  out[idx] = v / fmaxf(nrm, 1e-12f);
}

// ---------------- launch ----------------

extern "C" void kernel_launch(void* const* d_in, const int* in_sizes, int n_in,
                              void* d_out, int out_size, void* d_ws, size_t ws_size,
                              hipStream_t stream) {
  const float* x  = (const float*)d_in[0];
  const int*   ei = (const int*)d_in[1];
  const float* W1 = (const float*)d_in[2];
  const float* b1 = (const float*)d_in[3];
  const float* W2 = (const float*)d_in[4];
  const float* b2 = (const float*)d_in[5];
  const float* W3 = (const float*)d_in[6];
  const float* b3 = (const float*)d_in[7];
  const int N = in_sizes[0] / IN_F;
  const int E = in_sizes[1] / 2;
  const int* src = ei;
  const int* dst = ei + E;

  char* base = (char*)d_ws;
  const size_t szBig = (size_t)N * HID_F * sizeof(float);  // N x 256 fp32
  float* P    = (float*)(base);                 // N x 256
  float* Q    = (float*)(base + szBig);         // N x 256
  int*   deg  = (int*)  (base + 2 * szBig);
  float* dinv = (float*)(base + 2 * szBig + (size_t)N * sizeof(int));
  float* out  = (float*)d_out;

  // degrees (self loop included), dinv = deg^-1/2
  k_deg_init <<<(N + 255) / 256, 256, 0, stream>>>(deg, N);
  k_deg_accum<<<(E + 255) / 256, 256, 0, stream>>>(dst, deg, E);
  k_dinv     <<<(N + 255) / 256, 256, 0, stream>>>(deg, dinv, N);

  // ---- layer 1: aggregate first (F=128), then GEMM 128->256 (+b1, relu)
  float* xs   = P;                         // N x 128
  float* aggX = P + (size_t)N * IN_F;      // N x 128
  k_scale_x<<<((N * 32) + 255) / 256, 256, 0, stream>>>(x, dinv, xs, N * 32);
  hipMemcpyAsync(aggX, xs, (size_t)N * IN_F * sizeof(float), hipMemcpyDeviceToDevice, stream);
  {
    long long total = (long long)E * (IN_F / 4);
    k_scatter<IN_F><<<(int)((total + 255) / 256), 256, 0, stream>>>(xs, aggX, src, dst, total);
  }
  float* h1 = Q;  // N x 256
  {
    dim3 g((N + 63) / 64, HID_F / 64);
    k_gemm<1 | 4><<<g, 256, 0, stream>>>(aggX, W1, h1, N, IN_F, HID_F, dinv, b1);
  }

  // ---- layer 2: GEMM 256->256 (post-scale dinv), aggregate (F=256), bias+relu
  float* t2 = P;  // N x 256 (xs/aggX dead)
  {
    dim3 g((N + 63) / 64, HID_F / 64);
    k_gemm<2><<<g, 256, 0, stream>>>(h1, W2, t2, N, HID_F, HID_F, dinv, nullptr);
  }
  hipMemcpyAsync(Q, t2, szBig, hipMemcpyDeviceToDevice, stream);  // h1 dead; Q <- self-loop term
  {
    long long total = (long long)E * (HID_F / 4);
    k_scatter<HID_F><<<(int)((total + 255) / 256), 256, 0, stream>>>(t2, Q, src, dst, total);
  }
  k_bias_relu<<<((N * 64) + 255) / 256, 256, 0, stream>>>(Q, dinv, b2, N * 64);  // Q = h2

  // ---- layer 3: GEMM 256->64 (post-scale dinv), aggregate (F=64), bias+normalize
  float* t3 = P;  // N x 64
  {
    dim3 g((N + 63) / 64, EMB_F / 64);
    k_gemm<2><<<g, 256, 0, stream>>>(Q, W3, t3, N, HID_F, EMB_F, dinv, nullptr);
  }
  hipMemcpyAsync(out, t3, (size_t)N * EMB_F * sizeof(float), hipMemcpyDeviceToDevice, stream);
  {
    long long total = (long long)E * (EMB_F / 4);
    k_scatter<EMB_F><<<(int)((total + 255) / 256), 256, 0, stream>>>(t3, out, src, dst, total);
  }
  k_final<<<((N * 64) + 255) / 256, 256, 0, stream>>>(out, dinv, b3, N);
}

// Round 2
// 1092.718 us; speedup vs baseline: 9.0699x; 9.0699x over previous
//
#include <hip/hip_runtime.h>
#include <cstddef>
#include <cstdint>

constexpr int IN_F  = 128;
constexpr int HID_F = 256;
constexpr int EMB_F = 64;

// ---------------- degree / dinv ----------------

__global__ void k_deg_init(int* __restrict__ deg, int n) {
  int i = blockIdx.x * blockDim.x + threadIdx.x;
  if (i < n) deg[i] = 1;  // self loop
}

__global__ void k_deg_accum(const int* __restrict__ dst, int* __restrict__ deg, int e) {
  int i = blockIdx.x * blockDim.x + threadIdx.x;
  if (i < e) atomicAdd(&deg[dst[i]], 1);
}

__global__ void k_dinv(const int* __restrict__ deg, float* __restrict__ dinv, int n) {
  int i = blockIdx.x * blockDim.x + threadIdx.x;
  if (i < n) dinv[i] = rsqrtf((float)deg[i]);  // deg >= 1 always
}

// ---------------- exclusive scan of edge-degree (deg-1) -> rowptr ----------------

__global__ void k_scan1(const int* __restrict__ deg, int* __restrict__ rowptr,
                        int* __restrict__ bsum, int n) {
  __shared__ int s[256];
  int i = blockIdx.x * 256 + threadIdx.x;
  int v = (i < n) ? (deg[i] - 1) : 0;
  s[threadIdx.x] = v;
  __syncthreads();
#pragma unroll
  for (int off = 1; off < 256; off <<= 1) {
    int t = (threadIdx.x >= off) ? s[threadIdx.x - off] : 0;
    __syncthreads();
    s[threadIdx.x] += t;
    __syncthreads();
  }
  if (i < n) rowptr[i] = s[threadIdx.x] - v;  // exclusive
  if (threadIdx.x == 255) bsum[blockIdx.x] = s[255];
}

__global__ void k_scan2(int* __restrict__ bsum, int nb) {  // nb <= 512
  __shared__ int s[512];
  int v = (threadIdx.x < nb) ? bsum[threadIdx.x] : 0;
  s[threadIdx.x] = v;
  __syncthreads();
#pragma unroll
  for (int off = 1; off < 512; off <<= 1) {
    int t = (threadIdx.x >= off) ? s[threadIdx.x - off] : 0;
    __syncthreads();
    s[threadIdx.x] += t;
    __syncthreads();
  }
  if (threadIdx.x < nb) bsum[threadIdx.x] = s[threadIdx.x] - v;  // exclusive
}

__global__ void k_scan3(int* __restrict__ rowptr, const int* __restrict__ bsum,
                        int n, int e) {
  int i = blockIdx.x * blockDim.x + threadIdx.x;
  if (i < n) rowptr[i] += bsum[i >> 8];
  else if (i == n) rowptr[n] = e;
}

__global__ void k_zero_i32(int* __restrict__ p, int n) {
  int i = blockIdx.x * blockDim.x + threadIdx.x;
  if (i < n) p[i] = 0;
}

__global__ void k_csr_fill(const int* __restrict__ src, const int* __restrict__ dst,
                           const int* __restrict__ rowptr, int* __restrict__ cursor,
                           int* __restrict__ csr, int e) {
  int i = blockIdx.x * blockDim.x + threadIdx.x;
  if (i >= e) return;
  int d = dst[i];
  int pos = rowptr[d] + atomicAdd(&cursor[d], 1);
  csr[pos] = src[i];
}

// ---------------- gather aggregation: one wave per node ----------------
// MODE 0: acc = sum_{s in N(v) u {v}} t[s]*dinv[s]            (layer 1 pre-GEMM)
// MODE 1: out = relu( (sum t[s]) * dinv[v] + bias )           (layer 2 post-GEMM)
// MODE 2: v = (sum t[s]) * dinv[v] + bias; L2-normalize row   (layer 3, F=64)

template<int F, int MODE>
__global__ __launch_bounds__(256) void k_gather(
    const float* __restrict__ t, float* __restrict__ outp,
    const int* __restrict__ rowptr, const int* __restrict__ csr,
    const float* __restrict__ dinv, const float* __restrict__ bias, int n) {
  constexpr int VPL = F / 64;  // floats per lane: 4 / 2 / 1
  int wid = (blockIdx.x * blockDim.x + threadIdx.x) >> 6;
  int lane = threadIdx.x & 63;
  if (wid >= n) return;

  float acc[VPL];
  {
    const float* self = t + (size_t)wid * F + lane * VPL;
    float ss = (MODE == 0) ? dinv[wid] : 1.0f;
    if constexpr (VPL == 4) {
      float4 v = *reinterpret_cast<const float4*>(self);
      acc[0] = v.x * ss; acc[1] = v.y * ss; acc[2] = v.z * ss; acc[3] = v.w * ss;
    } else if constexpr (VPL == 2) {
      float2 v = *reinterpret_cast<const float2*>(self);
      acc[0] = v.x * ss; acc[1] = v.y * ss;
    } else {
      acc[0] = self[0] * ss;
    }
  }

  int beg = rowptr[wid], end = rowptr[wid + 1];
  int s_cur = (beg < end) ? csr[beg] : 0;
  for (int j = beg; j < end; ++j) {
    int s_next = (j + 1 < end) ? csr[j + 1] : 0;
    const float* row = t + (size_t)s_cur * F + lane * VPL;
    float es = (MODE == 0) ? dinv[s_cur] : 1.0f;
    if constexpr (VPL == 4) {
      float4 v = *reinterpret_cast<const float4*>(row);
      acc[0] = fmaf(v.x, es, acc[0]); acc[1] = fmaf(v.y, es, acc[1]);
      acc[2] = fmaf(v.z, es, acc[2]); acc[3] = fmaf(v.w, es, acc[3]);
    } else if constexpr (VPL == 2) {
      float2 v = *reinterpret_cast<const float2*>(row);
      acc[0] = fmaf(v.x, es, acc[0]); acc[1] = fmaf(v.y, es, acc[1]);
    } else {
      acc[0] = fmaf(row[0], es, acc[0]);
    }
    s_cur = s_next;
  }

  float* op = outp + (size_t)wid * F + lane * VPL;
  if constexpr (MODE == 0) {
    if constexpr (VPL == 4) {
      *reinterpret_cast<float4*>(op) = make_float4(acc[0], acc[1], acc[2], acc[3]);
    } else if constexpr (VPL == 2) {
      *reinterpret_cast<float2*>(op) = make_float2(acc[0], acc[1]);
    } else {
      op[0] = acc[0];
    }
  } else if constexpr (MODE == 1) {
    float s = dinv[wid];
    int c = lane * VPL;
#pragma unroll
    for (int k = 0; k < VPL; ++k) acc[k] = fmaxf(fmaf(acc[k], s, bias[c + k]), 0.f);
    if constexpr (VPL == 4) {
      *reinterpret_cast<float4*>(op) = make_float4(acc[0], acc[1], acc[2], acc[3]);
    } else if constexpr (VPL == 2) {
      *reinterpret_cast<float2*>(op) = make_float2(acc[0], acc[1]);
    } else {
      op[0] = acc[0];
    }
  } else {  // MODE 2, F=64, VPL=1
    float v = fmaf(acc[0], dinv[wid], bias[lane]);
    float ss = v * v;
#pragma unroll
    for (int off = 32; off > 0; off >>= 1) ss += __shfl_xor(ss, off);
    float nrm = sqrtf(ss);
    op[0] = v / fmaxf(nrm, 1e-12f);
  }
}

// ---------------- tiled fp32 GEMM: C[M,F] = op(A[M,K]) @ B[K,F] ----------------
// FLAGS bit0: scale A rows by dinv;  bit1: scale C rows by dinv;  bit2: +bias, relu

template<int FLAGS>
__global__ __launch_bounds__(256) void k_gemm(
    const float* __restrict__ A, const float* __restrict__ B, float* __restrict__ C,
    int M, int K, int F,
    const float* __restrict__ dinv, const float* __restrict__ bias) {
  __shared__ float As[64][68];  // transposed: As[k][m]
  __shared__ float Bs[64][68];
  const int tid = threadIdx.x;
  const int tx = tid & 15, ty = tid >> 4;
  const int bm = blockIdx.x * 64, bn = blockIdx.y * 64;
  float acc[4][4] = {};
  const int lrow = tid >> 4;            // 0..15
  const int lcol = (tid & 15) * 4;      // 0..60

  for (int k0 = 0; k0 < K; k0 += 64) {
#pragma unroll
    for (int r = 0; r < 4; ++r) {
      int row = lrow + r * 16;          // 0..63
      int grow = bm + row;
      float4 v = make_float4(0.f, 0.f, 0.f, 0.f);
      if (grow < M) {
        v = *reinterpret_cast<const float4*>(A + (size_t)grow * K + k0 + lcol);
        if (FLAGS & 1) { float s = dinv[grow]; v.x *= s; v.y *= s; v.z *= s; v.w *= s; }
      }
      As[lcol + 0][row] = v.x;
      As[lcol + 1][row] = v.y;
      As[lcol + 2][row] = v.z;
      As[lcol + 3][row] = v.w;
      float4 w = *reinterpret_cast<const float4*>(B + (size_t)(k0 + row) * F + bn + lcol);
      *reinterpret_cast<float4*>(&Bs[row][lcol]) = w;
    }
    __syncthreads();
#pragma unroll
    for (int kk = 0; kk < 64; ++kk) {
      float4 av = *reinterpret_cast<const float4*>(&As[kk][ty * 4]);
      float4 bv = *reinterpret_cast<const float4*>(&Bs[kk][tx * 4]);
      float a[4] = {av.x, av.y, av.z, av.w};
      float b[4] = {bv.x, bv.y, bv.z, bv.w};
#pragma unroll
      for (int i = 0; i < 4; ++i)
#pragma unroll
        for (int j = 0; j < 4; ++j)
          acc[i][j] = fmaf(a[i], b[j], acc[i][j]);
    }
    __syncthreads();
  }

#pragma unroll
  for (int i = 0; i < 4; ++i) {
    int grow = bm + ty * 4 + i;
    if (grow >= M) continue;
    float s = (FLAGS & 2) ? dinv[grow] : 1.0f;
#pragma unroll
    for (int j = 0; j < 4; ++j) {
      int gcol = bn + tx * 4 + j;
      float v = acc[i][j] * s;
      if (FLAGS & 4) v = fmaxf(v + bias[gcol], 0.f);
      C[(size_t)grow * F + gcol] = v;
    }
  }
}

// ---------------- launch ----------------

extern "C" void kernel_launch(void* const* d_in, const int* in_sizes, int n_in,
                              void* d_out, int out_size, void* d_ws, size_t ws_size,
                              hipStream_t stream) {
  const float* x  = (const float*)d_in[0];
  const int*   ei = (const int*)d_in[1];
  const float* W1 = (const float*)d_in[2];
  const float* b1 = (const float*)d_in[3];
  const float* W2 = (const float*)d_in[4];
  const float* b2 = (const float*)d_in[5];
  const float* W3 = (const float*)d_in[6];
  const float* b3 = (const float*)d_in[7];
  const int N = in_sizes[0] / IN_F;
  const int E = in_sizes[1] / 2;
  const int* src = ei;
  const int* dst = ei + E;

  char* base = (char*)d_ws;
  const size_t szBig = (size_t)N * HID_F * sizeof(float);  // N x 256 fp32
  float* P    = (float*)(base);                 // N x 256
  float* Q    = (float*)(base + szBig);         // N x 256
  char*  m    = base + 2 * szBig;
  int*   deg    = (int*)m;                 m += (size_t)N * 4;
  float* dinv   = (float*)m;               m += (size_t)N * 4;
  int*   rowptr = (int*)m;                 m += (size_t)(N + 1) * 4;
  int*   cursor = (int*)m;                 m += (size_t)N * 4;
  int*   bsum   = (int*)m;                 m += 512 * 4;
  int*   csr    = (int*)m;                 m += (size_t)E * 4;
  float* out  = (float*)d_out;

  const int nb = (N + 255) / 256;  // 391 <= 512 (k_scan2 capacity)

  // degrees (incl self loop), dinv = deg^-1/2
  k_deg_init <<<(N + 255) / 256, 256, 0, stream>>>(deg, N);
  k_deg_accum<<<(E + 255) / 256, 256, 0, stream>>>(dst, deg, E);
  k_dinv     <<<(N + 255) / 256, 256, 0, stream>>>(deg, dinv, N);

  // CSR build (edges grouped by dst; self loops handled in gather init)
  k_scan1<<<nb, 256, 0, stream>>>(deg, rowptr, bsum, N);
  k_scan2<<<1, 512, 0, stream>>>(bsum, nb);
  k_scan3<<<(N + 1 + 255) / 256, 256, 0, stream>>>(rowptr, bsum, N, E);
  k_zero_i32<<<(N + 255) / 256, 256, 0, stream>>>(cursor, N);
  k_csr_fill<<<(E + 255) / 256, 256, 0, stream>>>(src, dst, rowptr, cursor, csr, E);

  const int gwaves = (N + 3) / 4;  // 4 waves (nodes) per 256-thread block

  // ---- layer 1: gather x (F=128, dinv[src]-scaled), then GEMM 128->256 (+dinv row, +b1, relu)
  float* aggX = P;  // N x 128
  k_gather<IN_F, 0><<<gwaves, 256, 0, stream>>>(x, aggX, rowptr, csr, dinv, nullptr, N);
  float* h1 = Q;    // N x 256
  {
    dim3 g((N + 63) / 64, HID_F / 64);
    k_gemm<1 | 4><<<g, 256, 0, stream>>>(aggX, W1, h1, N, IN_F, HID_F, dinv, b1);
  }

  // ---- layer 2: GEMM 256->256 (post-scale dinv), gather (F=256) fused bias+relu
  float* t2 = P;  // N x 256 (aggX dead)
  {
    dim3 g((N + 63) / 64, HID_F / 64);
    k_gemm<2><<<g, 256, 0, stream>>>(h1, W2, t2, N, HID_F, HID_F, dinv, nullptr);
  }
  float* h2 = Q;  // h1 dead after GEMM above
  k_gather<HID_F, 1><<<gwaves, 256, 0, stream>>>(t2, h2, rowptr, csr, dinv, b2, N);

  // ---- layer 3: GEMM 256->64 (post-scale dinv), gather (F=64) fused bias + L2-normalize
  float* t3 = P;  // N x 64
  {
    dim3 g((N + 63) / 64, EMB_F / 64);
    k_gemm<2><<<g, 256, 0, stream>>>(h2, W3, t3, N, HID_F, EMB_F, dinv, nullptr);
  }
  k_gather<EMB_F, 2><<<gwaves, 256, 0, stream>>>(t3, out, rowptr, csr, dinv, b3, N);
}

// Round 3
// 654.980 us; speedup vs baseline: 15.1316x; 1.6683x over previous
//
#include <hip/hip_runtime.h>
#include <cstddef>
#include <cstdint>

constexpr int IN_F  = 128;
constexpr int HID_F = 256;
constexpr int EMB_F = 64;

typedef float  f32x4  __attribute__((ext_vector_type(4)));
typedef short  bf16x8 __attribute__((ext_vector_type(8)));
typedef unsigned short ushort_t;
typedef ushort_t u16x4 __attribute__((ext_vector_type(4)));
typedef ushort_t u16x2 __attribute__((ext_vector_type(2)));

__device__ inline float bf2f(ushort_t u) {
  union { unsigned i; float f; } c; c.i = ((unsigned)u) << 16; return c.f;
}
__device__ inline ushort_t f2bf(float f) {  // round-to-nearest-even
  union { float f; unsigned i; } c; c.f = f;
  unsigned r = c.i + 0x7FFFu + ((c.i >> 16) & 1u);
  return (ushort_t)(r >> 16);
}

// ---------------- degree / dinv ----------------

__global__ void k_deg_init(int* __restrict__ deg, int n) {
  int i = blockIdx.x * blockDim.x + threadIdx.x;
  if (i < n) deg[i] = 1;  // self loop
}
__global__ void k_deg_accum(const int* __restrict__ dst, int* __restrict__ deg, int e) {
  int i = blockIdx.x * blockDim.x + threadIdx.x;
  if (i < e) atomicAdd(&deg[dst[i]], 1);
}
__global__ void k_dinv(const int* __restrict__ deg, float* __restrict__ dinv, int n) {
  int i = blockIdx.x * blockDim.x + threadIdx.x;
  if (i < n) dinv[i] = rsqrtf((float)deg[i]);
}

// ---------------- exclusive scan of (deg-1) -> rowptr ----------------

__global__ void k_scan1(const int* __restrict__ deg, int* __restrict__ rowptr,
                        int* __restrict__ bsum, int n) {
  __shared__ int s[256];
  int i = blockIdx.x * 256 + threadIdx.x;
  int v = (i < n) ? (deg[i] - 1) : 0;
  s[threadIdx.x] = v;
  __syncthreads();
#pragma unroll
  for (int off = 1; off < 256; off <<= 1) {
    int t = (threadIdx.x >= off) ? s[threadIdx.x - off] : 0;
    __syncthreads();
    s[threadIdx.x] += t;
    __syncthreads();
  }
  if (i < n) rowptr[i] = s[threadIdx.x] - v;
  if (threadIdx.x == 255) bsum[blockIdx.x] = s[255];
}
__global__ void k_scan2(int* __restrict__ bsum, int nb) {  // nb <= 512
  __shared__ int s[512];
  int v = (threadIdx.x < nb) ? bsum[threadIdx.x] : 0;
  s[threadIdx.x] = v;
  __syncthreads();
#pragma unroll
  for (int off = 1; off < 512; off <<= 1) {
    int t = (threadIdx.x >= off) ? s[threadIdx.x - off] : 0;
    __syncthreads();
    s[threadIdx.x] += t;
    __syncthreads();
  }
  if (threadIdx.x < nb) bsum[threadIdx.x] = s[threadIdx.x] - v;
}
__global__ void k_scan3(int* __restrict__ rowptr, const int* __restrict__ bsum,
                        int n, int e) {
  int i = blockIdx.x * blockDim.x + threadIdx.x;
  if (i < n) rowptr[i] += bsum[i >> 8];
  else if (i == n) rowptr[n] = e;
}
__global__ void k_zero_i32(int* __restrict__ p, int n) {
  int i = blockIdx.x * blockDim.x + threadIdx.x;
  if (i < n) p[i] = 0;
}
__global__ void k_csr_fill(const int* __restrict__ src, const int* __restrict__ dst,
                           const int* __restrict__ rowptr, int* __restrict__ cursor,
                           int* __restrict__ csr, int e) {
  int i = blockIdx.x * blockDim.x + threadIdx.x;
  if (i >= e) return;
  int d = dst[i];
  int pos = rowptr[d] + atomicAdd(&cursor[d], 1);
  csr[pos] = src[i];
}

// ---------------- weight convert+transpose: Wt[n][k] = bf16(W[k][n]) ----------------

__global__ void k_wt(const float* __restrict__ W, ushort_t* __restrict__ Wt,
                     int K, int Nc) {
  int i = blockIdx.x * blockDim.x + threadIdx.x;
  if (i >= K * Nc) return;
  int k = i / Nc, n = i - k * Nc;
  Wt[(size_t)n * K + k] = f2bf(W[i]);
}

// ---------------- gathers (one wave per node, fp32 accumulate) ----------------

// layer 1: acc = sum_{s in N(v) u {v}} x[s]*dinv[s]   (x fp32, out bf16, F=128)
__global__ __launch_bounds__(256) void k_gather1(
    const float* __restrict__ x, ushort_t* __restrict__ outp,
    const int* __restrict__ rowptr, const int* __restrict__ csr,
    const float* __restrict__ dinv, int n) {
  int wid = (blockIdx.x * blockDim.x + threadIdx.x) >> 6;
  int lane = threadIdx.x & 63;
  if (wid >= n) return;
  float a0, a1;
  {
    float2 v = *reinterpret_cast<const float2*>(x + (size_t)wid * IN_F + lane * 2);
    float s = dinv[wid];
    a0 = v.x * s; a1 = v.y * s;
  }
  int beg = rowptr[wid], end = rowptr[wid + 1];
  int j = beg;
  for (; j + 1 < end; j += 2) {
    int s0 = csr[j], s1 = csr[j + 1];
    float2 v0 = *reinterpret_cast<const float2*>(x + (size_t)s0 * IN_F + lane * 2);
    float2 v1 = *reinterpret_cast<const float2*>(x + (size_t)s1 * IN_F + lane * 2);
    float d0 = dinv[s0], d1 = dinv[s1];
    a0 = fmaf(v0.x, d0, a0); a1 = fmaf(v0.y, d0, a1);
    a0 = fmaf(v1.x, d1, a0); a1 = fmaf(v1.y, d1, a1);
  }
  if (j < end) {
    int s0 = csr[j];
    float2 v0 = *reinterpret_cast<const float2*>(x + (size_t)s0 * IN_F + lane * 2);
    float d0 = dinv[s0];
    a0 = fmaf(v0.x, d0, a0); a1 = fmaf(v0.y, d0, a1);
  }
  u16x2 o; o[0] = f2bf(a0); o[1] = f2bf(a1);
  *reinterpret_cast<u16x2*>(outp + (size_t)wid * IN_F + lane * 2) = o;
}

// layer 2: out = relu( (sum_{s} t[s]) * dinv[v] + bias )   (bf16 in/out, F=256)
__global__ __launch_bounds__(256) void k_gather2(
    const ushort_t* __restrict__ t, ushort_t* __restrict__ outp,
    const int* __restrict__ rowptr, const int* __restrict__ csr,
    const float* __restrict__ dinv, const float* __restrict__ bias, int n) {
  int wid = (blockIdx.x * blockDim.x + threadIdx.x) >> 6;
  int lane = threadIdx.x & 63;
  if (wid >= n) return;
  float acc[4];
  {
    u16x4 v = *reinterpret_cast<const u16x4*>(t + (size_t)wid * HID_F + lane * 4);
#pragma unroll
    for (int k = 0; k < 4; ++k) acc[k] = bf2f(v[k]);
  }
  int beg = rowptr[wid], end = rowptr[wid + 1];
  int j = beg;
  for (; j + 1 < end; j += 2) {
    int s0 = csr[j], s1 = csr[j + 1];
    u16x4 v0 = *reinterpret_cast<const u16x4*>(t + (size_t)s0 * HID_F + lane * 4);
    u16x4 v1 = *reinterpret_cast<const u16x4*>(t + (size_t)s1 * HID_F + lane * 4);
#pragma unroll
    for (int k = 0; k < 4; ++k) acc[k] += bf2f(v0[k]);
#pragma unroll
    for (int k = 0; k < 4; ++k) acc[k] += bf2f(v1[k]);
  }
  if (j < end) {
    int s0 = csr[j];
    u16x4 v0 = *reinterpret_cast<const u16x4*>(t + (size_t)s0 * HID_F + lane * 4);
#pragma unroll
    for (int k = 0; k < 4; ++k) acc[k] += bf2f(v0[k]);
  }
  float s = dinv[wid];
  int c = lane * 4;
  u16x4 o;
#pragma unroll
  for (int k = 0; k < 4; ++k) o[k] = f2bf(fmaxf(fmaf(acc[k], s, bias[c + k]), 0.f));
  *reinterpret_cast<u16x4*>(outp + (size_t)wid * HID_F + lane * 4) = o;
}

// layer 3: v = (sum_{s} t[s]) * dinv[v] + b3; L2-normalize row  (bf16 in, fp32 out, F=64)
__global__ __launch_bounds__(256) void k_gather3(
    const ushort_t* __restrict__ t, float* __restrict__ outp,
    const int* __restrict__ rowptr, const int* __restrict__ csr,
    const float* __restrict__ dinv, const float* __restrict__ b3, int n) {
  int wid = (blockIdx.x * blockDim.x + threadIdx.x) >> 6;
  int lane = threadIdx.x & 63;
  if (wid >= n) return;
  float a = bf2f(t[(size_t)wid * EMB_F + lane]);
  int beg = rowptr[wid], end = rowptr[wid + 1];
  int j = beg;
  for (; j + 1 < end; j += 2) {
    int s0 = csr[j], s1 = csr[j + 1];
    float v0 = bf2f(t[(size_t)s0 * EMB_F + lane]);
    float v1 = bf2f(t[(size_t)s1 * EMB_F + lane]);
    a += v0; a += v1;
  }
  if (j < end) a += bf2f(t[(size_t)csr[j] * EMB_F + lane]);
  float v = fmaf(a, dinv[wid], b3[lane]);
  float ss = v * v;
#pragma unroll
  for (int off = 32; off > 0; off >>= 1) ss += __shfl_xor(ss, off);
  float nrm = sqrtf(ss);
  outp[(size_t)wid * EMB_F + lane] = v / fmaxf(nrm, 1e-12f);
}

// ---------------- LDS-free MFMA GEMM ----------------
// C[M][N] = dinv[row] * (A[M][K] @ Wt[N][K]^T)  (+bias, relu if RELU)
// wave-tile 64x64; mfma_f32_16x16x32_bf16; A,Wt,C bf16; acc fp32.
// frag layout: A lane: row=l&15, k=(l>>4)*8+j ; B lane: col=l&15, k=(l>>4)*8+j
// C/D (m89-verified): col=lane&15, row=(lane>>4)*4+reg

template<int K, bool RELU>
__global__ __launch_bounds__(256) void k_mfma_gemm(
    const ushort_t* __restrict__ A, const ushort_t* __restrict__ Wt,
    ushort_t* __restrict__ C,
    const float* __restrict__ dinv, const float* __restrict__ bias,
    int M, int NT /* N/64 */) {
  int w = blockIdx.x * 4 + (threadIdx.x >> 6);
  int lane = threadIdx.x & 63;
  int mt = w / NT, nt = w - mt * NT;
  int mbase = mt * 64, nbase = nt * 64;
  if (mbase >= M) return;
  const int lrow = lane & 15;
  const int lk = (lane >> 4) * 8;
  const int N = NT * 64;

  int rows[4];
#pragma unroll
  for (int i = 0; i < 4; ++i) {
    int r = mbase + i * 16 + lrow;
    rows[i] = (r < M) ? r : (M - 1);  // clamp loads; stores guarded
  }

  f32x4 acc[4][4] = {};

#pragma unroll 2
  for (int k0 = 0; k0 < K; k0 += 32) {
    bf16x8 a[4], b[4];
#pragma unroll
    for (int i = 0; i < 4; ++i)
      a[i] = *reinterpret_cast<const bf16x8*>(A + (size_t)rows[i] * K + k0 + lk);
#pragma unroll
    for (int n = 0; n < 4; ++n)
      b[n] = *reinterpret_cast<const bf16x8*>(Wt + (size_t)(nbase + n * 16 + lrow) * K + k0 + lk);
#pragma unroll
    for (int i = 0; i < 4; ++i)
#pragma unroll
      for (int n = 0; n < 4; ++n)
        acc[i][n] = __builtin_amdgcn_mfma_f32_16x16x32_bf16(a[i], b[n], acc[i][n], 0, 0, 0);
  }

#pragma unroll
  for (int i = 0; i < 4; ++i) {
    int growb = mbase + i * 16 + (lane >> 4) * 4;
#pragma unroll
    for (int r = 0; r < 4; ++r) {
      int grow = growb + r;
      if (grow >= M) continue;
      float s = dinv[grow];
#pragma unroll
      for (int n = 0; n < 4; ++n) {
        int gcol = nbase + n * 16 + (lane & 15);
        float v = acc[i][n][r] * s;
        if (RELU) v = fmaxf(v + bias[gcol], 0.f);
        C[(size_t)grow * N + gcol] = f2bf(v);
      }
    }
  }
}

// ---------------- launch ----------------

extern "C" void kernel_launch(void* const* d_in, const int* in_sizes, int n_in,
                              void* d_out, int out_size, void* d_ws, size_t ws_size,
                              hipStream_t stream) {
  const float* x  = (const float*)d_in[0];
  const int*   ei = (const int*)d_in[1];
  const float* W1 = (const float*)d_in[2];
  const float* b1 = (const float*)d_in[3];
  const float* W2 = (const float*)d_in[4];
  const float* b2 = (const float*)d_in[5];
  const float* W3 = (const float*)d_in[6];
  const float* b3 = (const float*)d_in[7];
  const int N = in_sizes[0] / IN_F;
  const int E = in_sizes[1] / 2;
  const int* src = ei;
  const int* dst = ei + E;

  char* m = (char*)d_ws;
  auto alloc = [&](size_t bytes) { char* p = m; m += (bytes + 255) & ~(size_t)255; return p; };
  ushort_t* U1  = (ushort_t*)alloc((size_t)N * HID_F * 2);  // N x 256 bf16
  ushort_t* U2  = (ushort_t*)alloc((size_t)N * HID_F * 2);
  ushort_t* W1t = (ushort_t*)alloc((size_t)IN_F * HID_F * 2);
  ushort_t* W2t = (ushort_t*)alloc((size_t)HID_F * HID_F * 2);
  ushort_t* W3t = (ushort_t*)alloc((size_t)HID_F * EMB_F * 2);
  int*   deg    = (int*)alloc((size_t)N * 4);
  float* dinv   = (float*)alloc((size_t)N * 4);
  int*   rowptr = (int*)alloc((size_t)(N + 1) * 4);
  int*   cursor = (int*)alloc((size_t)N * 4);
  int*   bsum   = (int*)alloc(512 * 4);
  int*   csr    = (int*)alloc((size_t)E * 4);
  float* out    = (float*)d_out;

  const int nb = (N + 255) / 256;  // <= 512

  // weights -> bf16 transposed
  k_wt<<<(IN_F * HID_F + 255) / 256, 256, 0, stream>>>(W1, W1t, IN_F, HID_F);
  k_wt<<<(HID_F * HID_F + 255) / 256, 256, 0, stream>>>(W2, W2t, HID_F, HID_F);
  k_wt<<<(HID_F * EMB_F + 255) / 256, 256, 0, stream>>>(W3, W3t, HID_F, EMB_F);

  // degrees (incl self loop), dinv
  k_deg_init <<<(N + 255) / 256, 256, 0, stream>>>(deg, N);
  k_deg_accum<<<(E + 255) / 256, 256, 0, stream>>>(dst, deg, E);
  k_dinv     <<<(N + 255) / 256, 256, 0, stream>>>(deg, dinv, N);

  // CSR (edges grouped by dst)
  k_scan1<<<nb, 256, 0, stream>>>(deg, rowptr, bsum, N);
  k_scan2<<<1, 512, 0, stream>>>(bsum, nb);
  k_scan3<<<(N + 1 + 255) / 256, 256, 0, stream>>>(rowptr, bsum, N, E);
  k_zero_i32<<<(N + 255) / 256, 256, 0, stream>>>(cursor, N);
  k_csr_fill<<<(E + 255) / 256, 256, 0, stream>>>(src, dst, rowptr, cursor, csr, E);

  const int gblocks = (N + 3) / 4;  // 4 waves per block, 1 node per wave
  const int MT = (N + 63) / 64;

  // layer 1: gather x (dinv[src]) -> aggX bf16 [N,128]; GEMM 128->256 (+dinv row, +b1, relu)
  ushort_t* aggX = U1;
  k_gather1<<<gblocks, 256, 0, stream>>>(x, aggX, rowptr, csr, dinv, N);
  ushort_t* h1 = U2;
  k_mfma_gemm<IN_F, true><<<(MT * (HID_F / 64) + 3) / 4, 256, 0, stream>>>(
      aggX, W1t, h1, dinv, b1, N, HID_F / 64);

  // layer 2: GEMM 256->256 (dinv row) -> t2; gather (+dinv, b2, relu) -> h2
  ushort_t* t2 = U1;
  k_mfma_gemm<HID_F, false><<<(MT * (HID_F / 64) + 3) / 4, 256, 0, stream>>>(
      h1, W2t, t2, dinv, nullptr, N, HID_F / 64);
  ushort_t* h2 = U2;
  k_gather2<<<gblocks, 256, 0, stream>>>(t2, h2, rowptr, csr, dinv, b2, N);

  // layer 3: GEMM 256->64 (dinv row) -> t3; gather (+dinv, b3) + L2-normalize -> out
  ushort_t* t3 = U1;
  k_mfma_gemm<HID_F, false><<<(MT * (EMB_F / 64) + 3) / 4, 256, 0, stream>>>(
      h2, W3t, t3, dinv, nullptr, N, EMB_F / 64);
  k_gather3<<<gblocks, 256, 0, stream>>>(t3, out, rowptr, csr, dinv, b3, N);
}

// Round 4
// 594.353 us; speedup vs baseline: 16.6751x; 1.1020x over previous
//
#include <hip/hip_runtime.h>
#include <cstddef>
#include <cstdint>

constexpr int IN_F  = 128;
constexpr int HID_F = 256;
constexpr int EMB_F = 64;

typedef float  f32x4  __attribute__((ext_vector_type(4)));
typedef short  bf16x8 __attribute__((ext_vector_type(8)));
typedef unsigned short ushort_t;
typedef ushort_t u16x4 __attribute__((ext_vector_type(4)));
typedef ushort_t u16x2 __attribute__((ext_vector_type(2)));

__device__ inline float bf2f(ushort_t u) {
  union { unsigned i; float f; } c; c.i = ((unsigned)u) << 16; return c.f;
}
__device__ inline ushort_t f2bf(float f) {  // round-to-nearest-even
  union { float f; unsigned i; } c; c.f = f;
  unsigned r = c.i + 0x7FFFu + ((c.i >> 16) & 1u);
  return (ushort_t)(r >> 16);
}

// ---------------- fused setup: deg=1, three weight transposes to bf16 ----------------
// ranges: [0,c1) W1, [c1,c2) W2, [c2,c3) W3, [c3,c3+N) deg

__global__ void k_setup(const float* __restrict__ W1, const float* __restrict__ W2,
                        const float* __restrict__ W3,
                        ushort_t* __restrict__ W1t, ushort_t* __restrict__ W2t,
                        ushort_t* __restrict__ W3t,
                        int* __restrict__ deg, int n) {
  constexpr int c1 = IN_F * HID_F;
  constexpr int c2 = c1 + HID_F * HID_F;
  constexpr int c3 = c2 + HID_F * EMB_F;
  int i = blockIdx.x * blockDim.x + threadIdx.x;
  if (i < c1) {
    int k = i / HID_F, nn = i - k * HID_F;
    W1t[(size_t)nn * IN_F + k] = f2bf(W1[i]);
  } else if (i < c2) {
    int j = i - c1;
    int k = j / HID_F, nn = j - k * HID_F;
    W2t[(size_t)nn * HID_F + k] = f2bf(W2[j]);
  } else if (i < c3) {
    int j = i - c2;
    int k = j / EMB_F, nn = j - k * EMB_F;
    W3t[(size_t)nn * HID_F + k] = f2bf(W3[j]);
  } else if (i - c3 < n) {
    deg[i - c3] = 1;  // self loop
  }
}

__global__ void k_deg_accum(const int* __restrict__ dst, int* __restrict__ deg, int e) {
  int i = blockIdx.x * blockDim.x + threadIdx.x;
  if (i < e) atomicAdd(&deg[dst[i]], 1);
}

// ---------------- scan of (deg-1) -> rowptr; also dinv = rsqrt(deg) ----------------

__global__ void k_scan1(const int* __restrict__ deg, int* __restrict__ rowptr,
                        int* __restrict__ bsum, float* __restrict__ dinv, int n) {
  __shared__ int s[256];
  int i = blockIdx.x * 256 + threadIdx.x;
  int v = (i < n) ? (deg[i] - 1) : 0;
  if (i < n) dinv[i] = rsqrtf((float)deg[i]);
  s[threadIdx.x] = v;
  __syncthreads();
#pragma unroll
  for (int off = 1; off < 256; off <<= 1) {
    int t = (threadIdx.x >= off) ? s[threadIdx.x - off] : 0;
    __syncthreads();
    s[threadIdx.x] += t;
    __syncthreads();
  }
  if (i < n) rowptr[i] = s[threadIdx.x] - v;
  if (threadIdx.x == 255) bsum[blockIdx.x] = s[255];
}

__global__ void k_scan2(int* __restrict__ bsum, int nb) {  // nb <= 512
  __shared__ int s[512];
  int v = (threadIdx.x < nb) ? bsum[threadIdx.x] : 0;
  s[threadIdx.x] = v;
  __syncthreads();
#pragma unroll
  for (int off = 1; off < 512; off <<= 1) {
    int t = (threadIdx.x >= off) ? s[threadIdx.x - off] : 0;
    __syncthreads();
    s[threadIdx.x] += t;
    __syncthreads();
  }
  if (threadIdx.x < nb) bsum[threadIdx.x] = s[threadIdx.x] - v;
}

// finalize rowptr, copy into cursor (csr_fill atomics give absolute positions)
__global__ void k_scan3(int* __restrict__ rowptr, const int* __restrict__ bsum,
                        int* __restrict__ cursor, int n, int e) {
  int i = blockIdx.x * blockDim.x + threadIdx.x;
  if (i < n) {
    int v = rowptr[i] + bsum[i >> 8];
    rowptr[i] = v;
    cursor[i] = v;
  } else if (i == n) {
    rowptr[n] = e;
  }
}

__global__ void k_csr_fill(const int* __restrict__ src, const int* __restrict__ dst,
                           int* __restrict__ cursor, int* __restrict__ csr, int e) {
  int i = blockIdx.x * blockDim.x + threadIdx.x;
  if (i >= e) return;
  int pos = atomicAdd(&cursor[dst[i]], 1);
  csr[pos] = src[i];
}

// ---------------- xb = bf16(x * dinv[row])  (N*32 float4 -> u16x4) ----------------

__global__ void k_xconv(const float* __restrict__ x, const float* __restrict__ dinv,
                        ushort_t* __restrict__ xb, int n4 /* N*32 */) {
  int i = blockIdx.x * blockDim.x + threadIdx.x;
  if (i >= n4) return;
  float s = dinv[i >> 5];
  float4 v = reinterpret_cast<const float4*>(x)[i];
  u16x4 o;
  o[0] = f2bf(v.x * s); o[1] = f2bf(v.y * s); o[2] = f2bf(v.z * s); o[3] = f2bf(v.w * s);
  reinterpret_cast<u16x4*>(xb)[i] = o;
}

// ---------------- gathers (one wave per node, fp32 accumulate, 4-edge unroll) ----------------

// layer 1: acc = sum_{s in N(v) u {v}} xb[s]   (xb bf16 pre-scaled, out bf16, F=128)
__global__ __launch_bounds__(256) void k_gather1(
    const ushort_t* __restrict__ t, ushort_t* __restrict__ outp,
    const int* __restrict__ rowptr, const int* __restrict__ csr, int n) {
  int wid = (blockIdx.x * blockDim.x + threadIdx.x) >> 6;
  int lane = threadIdx.x & 63;
  if (wid >= n) return;
  float a0, a1;
  {
    u16x2 v = *reinterpret_cast<const u16x2*>(t + (size_t)wid * IN_F + lane * 2);
    a0 = bf2f(v[0]); a1 = bf2f(v[1]);
  }
  int beg = rowptr[wid], end = rowptr[wid + 1];
  int j = beg;
  for (; j + 3 < end; j += 4) {
    int s0 = csr[j], s1 = csr[j + 1], s2 = csr[j + 2], s3 = csr[j + 3];
    u16x2 v0 = *reinterpret_cast<const u16x2*>(t + (size_t)s0 * IN_F + lane * 2);
    u16x2 v1 = *reinterpret_cast<const u16x2*>(t + (size_t)s1 * IN_F + lane * 2);
    u16x2 v2 = *reinterpret_cast<const u16x2*>(t + (size_t)s2 * IN_F + lane * 2);
    u16x2 v3 = *reinterpret_cast<const u16x2*>(t + (size_t)s3 * IN_F + lane * 2);
    a0 += bf2f(v0[0]); a1 += bf2f(v0[1]);
    a0 += bf2f(v1[0]); a1 += bf2f(v1[1]);
    a0 += bf2f(v2[0]); a1 += bf2f(v2[1]);
    a0 += bf2f(v3[0]); a1 += bf2f(v3[1]);
  }
  for (; j < end; ++j) {
    int s0 = csr[j];
    u16x2 v0 = *reinterpret_cast<const u16x2*>(t + (size_t)s0 * IN_F + lane * 2);
    a0 += bf2f(v0[0]); a1 += bf2f(v0[1]);
  }
  u16x2 o; o[0] = f2bf(a0); o[1] = f2bf(a1);
  *reinterpret_cast<u16x2*>(outp + (size_t)wid * IN_F + lane * 2) = o;
}

// layer 2: out = relu( (sum_{s} t[s]) * dinv[v] + bias )   (bf16 in/out, F=256)
__global__ __launch_bounds__(256) void k_gather2(
    const ushort_t* __restrict__ t, ushort_t* __restrict__ outp,
    const int* __restrict__ rowptr, const int* __restrict__ csr,
    const float* __restrict__ dinv, const float* __restrict__ bias, int n) {
  int wid = (blockIdx.x * blockDim.x + threadIdx.x) >> 6;
  int lane = threadIdx.x & 63;
  if (wid >= n) return;
  float acc[4];
  {
    u16x4 v = *reinterpret_cast<const u16x4*>(t + (size_t)wid * HID_F + lane * 4);
#pragma unroll
    for (int k = 0; k < 4; ++k) acc[k] = bf2f(v[k]);
  }
  int beg = rowptr[wid], end = rowptr[wid + 1];
  int j = beg;
  for (; j + 3 < end; j += 4) {
    int s0 = csr[j], s1 = csr[j + 1], s2 = csr[j + 2], s3 = csr[j + 3];
    u16x4 v0 = *reinterpret_cast<const u16x4*>(t + (size_t)s0 * HID_F + lane * 4);
    u16x4 v1 = *reinterpret_cast<const u16x4*>(t + (size_t)s1 * HID_F + lane * 4);
    u16x4 v2 = *reinterpret_cast<const u16x4*>(t + (size_t)s2 * HID_F + lane * 4);
    u16x4 v3 = *reinterpret_cast<const u16x4*>(t + (size_t)s3 * HID_F + lane * 4);
#pragma unroll
    for (int k = 0; k < 4; ++k) acc[k] += bf2f(v0[k]);
#pragma unroll
    for (int k = 0; k < 4; ++k) acc[k] += bf2f(v1[k]);
#pragma unroll
    for (int k = 0; k < 4; ++k) acc[k] += bf2f(v2[k]);
#pragma unroll
    for (int k = 0; k < 4; ++k) acc[k] += bf2f(v3[k]);
  }
  for (; j < end; ++j) {
    int s0 = csr[j];
    u16x4 v0 = *reinterpret_cast<const u16x4*>(t + (size_t)s0 * HID_F + lane * 4);
#pragma unroll
    for (int k = 0; k < 4; ++k) acc[k] += bf2f(v0[k]);
  }
  float s = dinv[wid];
  int c = lane * 4;
  u16x4 o;
#pragma unroll
  for (int k = 0; k < 4; ++k) o[k] = f2bf(fmaxf(fmaf(acc[k], s, bias[c + k]), 0.f));
  *reinterpret_cast<u16x4*>(outp + (size_t)wid * HID_F + lane * 4) = o;
}

// layer 3: v = (sum_{s} t[s]) * dinv[v] + b3; L2-normalize row  (bf16 in, fp32 out, F=64)
__global__ __launch_bounds__(256) void k_gather3(
    const ushort_t* __restrict__ t, float* __restrict__ outp,
    const int* __restrict__ rowptr, const int* __restrict__ csr,
    const float* __restrict__ dinv, const float* __restrict__ b3, int n) {
  int wid = (blockIdx.x * blockDim.x + threadIdx.x) >> 6;
  int lane = threadIdx.x & 63;
  if (wid >= n) return;
  float a = bf2f(t[(size_t)wid * EMB_F + lane]);
  int beg = rowptr[wid], end = rowptr[wid + 1];
  int j = beg;
  for (; j + 3 < end; j += 4) {
    int s0 = csr[j], s1 = csr[j + 1], s2 = csr[j + 2], s3 = csr[j + 3];
    float v0 = bf2f(t[(size_t)s0 * EMB_F + lane]);
    float v1 = bf2f(t[(size_t)s1 * EMB_F + lane]);
    float v2 = bf2f(t[(size_t)s2 * EMB_F + lane]);
    float v3 = bf2f(t[(size_t)s3 * EMB_F + lane]);
    a += v0; a += v1; a += v2; a += v3;
  }
  for (; j < end; ++j) a += bf2f(t[(size_t)csr[j] * EMB_F + lane]);
  float v = fmaf(a, dinv[wid], b3[lane]);
  float ss = v * v;
#pragma unroll
  for (int off = 32; off > 0; off >>= 1) ss += __shfl_xor(ss, off);
  float nrm = sqrtf(ss);
  outp[(size_t)wid * EMB_F + lane] = v / fmaxf(nrm, 1e-12f);
}

// ---------------- LDS-free MFMA GEMM ----------------
// C[M][N] = dinv[row] * (A[M][K] @ Wt[N][K]^T)  (+bias, relu if RELU)
// wave-tile 64x64; mfma_f32_16x16x32_bf16; A,Wt,C bf16; acc fp32.
// C/D (m89-verified): col=lane&15, row=(lane>>4)*4+reg

template<int K, bool RELU>
__global__ __launch_bounds__(256) void k_mfma_gemm(
    const ushort_t* __restrict__ A, const ushort_t* __restrict__ Wt,
    ushort_t* __restrict__ C,
    const float* __restrict__ dinv, const float* __restrict__ bias,
    int M, int NT /* N/64 */) {
  int w = blockIdx.x * 4 + (threadIdx.x >> 6);
  int lane = threadIdx.x & 63;
  int mt = w / NT, nt = w - mt * NT;
  int mbase = mt * 64, nbase = nt * 64;
  if (mbase >= M) return;
  const int lrow = lane & 15;
  const int lk = (lane >> 4) * 8;
  const int N = NT * 64;

  int rows[4];
#pragma unroll
  for (int i = 0; i < 4; ++i) {
    int r = mbase + i * 16 + lrow;
    rows[i] = (r < M) ? r : (M - 1);  // clamp loads; stores guarded
  }

  f32x4 acc[4][4] = {};

#pragma unroll 2
  for (int k0 = 0; k0 < K; k0 += 32) {
    bf16x8 a[4], b[4];
#pragma unroll
    for (int i = 0; i < 4; ++i)
      a[i] = *reinterpret_cast<const bf16x8*>(A + (size_t)rows[i] * K + k0 + lk);
#pragma unroll
    for (int n = 0; n < 4; ++n)
      b[n] = *reinterpret_cast<const bf16x8*>(Wt + (size_t)(nbase + n * 16 + lrow) * K + k0 + lk);
#pragma unroll
    for (int i = 0; i < 4; ++i)
#pragma unroll
      for (int n = 0; n < 4; ++n)
        acc[i][n] = __builtin_amdgcn_mfma_f32_16x16x32_bf16(a[i], b[n], acc[i][n], 0, 0, 0);
  }

#pragma unroll
  for (int i = 0; i < 4; ++i) {
    int growb = mbase + i * 16 + (lane >> 4) * 4;
#pragma unroll
    for (int r = 0; r < 4; ++r) {
      int grow = growb + r;
      if (grow >= M) continue;
      float s = dinv[grow];
#pragma unroll
      for (int n = 0; n < 4; ++n) {
        int gcol = nbase + n * 16 + (lane & 15);
        float v = acc[i][n][r] * s;
        if (RELU) v = fmaxf(v + bias[gcol], 0.f);
        C[(size_t)grow * N + gcol] = f2bf(v);
      }
    }
  }
}

// ---------------- launch ----------------

extern "C" void kernel_launch(void* const* d_in, const int* in_sizes, int n_in,
                              void* d_out, int out_size, void* d_ws, size_t ws_size,
                              hipStream_t stream) {
  const float* x  = (const float*)d_in[0];
  const int*   ei = (const int*)d_in[1];
  const float* W1 = (const float*)d_in[2];
  const float* b1 = (const float*)d_in[3];
  const float* W2 = (const float*)d_in[4];
  const float* b2 = (const float*)d_in[5];
  const float* W3 = (const float*)d_in[6];
  const float* b3 = (const float*)d_in[7];
  const int N = in_sizes[0] / IN_F;
  const int E = in_sizes[1] / 2;
  const int* src = ei;
  const int* dst = ei + E;

  char* m = (char*)d_ws;
  auto alloc = [&](size_t bytes) { char* p = m; m += (bytes + 255) & ~(size_t)255; return p; };
  ushort_t* U1  = (ushort_t*)alloc((size_t)N * HID_F * 2);  // N x 256 bf16
  ushort_t* U2  = (ushort_t*)alloc((size_t)N * HID_F * 2);
  ushort_t* W1t = (ushort_t*)alloc((size_t)IN_F * HID_F * 2);
  ushort_t* W2t = (ushort_t*)alloc((size_t)HID_F * HID_F * 2);
  ushort_t* W3t = (ushort_t*)alloc((size_t)HID_F * EMB_F * 2);
  int*   deg    = (int*)alloc((size_t)N * 4);
  float* dinv   = (float*)alloc((size_t)N * 4);
  int*   rowptr = (int*)alloc((size_t)(N + 1) * 4);
  int*   cursor = (int*)alloc((size_t)N * 4);
  int*   bsum   = (int*)alloc(512 * 4);
  int*   csr    = (int*)alloc((size_t)E * 4);
  float* out    = (float*)d_out;

  const int nb = (N + 255) / 256;  // <= 512 (k_scan2 capacity)
  constexpr int SETUP_W = IN_F * HID_F + HID_F * HID_F + HID_F * EMB_F;

  // fused: weight transposes + deg=1
  k_setup<<<(SETUP_W + N + 255) / 256, 256, 0, stream>>>(W1, W2, W3, W1t, W2t, W3t, deg, N);
  k_deg_accum<<<(E + 255) / 256, 256, 0, stream>>>(dst, deg, E);

  // scan (deg-1) -> rowptr; dinv; cursor = rowptr
  k_scan1<<<nb, 256, 0, stream>>>(deg, rowptr, bsum, dinv, N);
  k_scan2<<<1, 512, 0, stream>>>(bsum, nb);
  k_scan3<<<(N + 1 + 255) / 256, 256, 0, stream>>>(rowptr, bsum, cursor, N, E);

  // xb = bf16(x * dinv)  (aliased into U2; dead before gemm1 writes U2)
  ushort_t* xb = U2;
  k_xconv<<<((N * 32) + 255) / 256, 256, 0, stream>>>(x, dinv, xb, N * 32);

  // CSR fill (edges grouped by dst)
  k_csr_fill<<<(E + 255) / 256, 256, 0, stream>>>(src, dst, cursor, csr, E);

  const int gblocks = (N + 3) / 4;  // 4 waves per block, 1 node per wave
  const int MT = (N + 63) / 64;

  // layer 1: gather xb -> aggX bf16 [N,128]; GEMM 128->256 (+dinv row, +b1, relu)
  ushort_t* aggX = U1;
  k_gather1<<<gblocks, 256, 0, stream>>>(xb, aggX, rowptr, csr, N);
  ushort_t* h1 = U2;
  k_mfma_gemm<IN_F, true><<<(MT * (HID_F / 64) + 3) / 4, 256, 0, stream>>>(
      aggX, W1t, h1, dinv, b1, N, HID_F / 64);

  // layer 2: GEMM 256->256 (dinv row) -> t2; gather (+dinv, b2, relu) -> h2
  ushort_t* t2 = U1;
  k_mfma_gemm<HID_F, false><<<(MT * (HID_F / 64) + 3) / 4, 256, 0, stream>>>(
      h1, W2t, t2, dinv, nullptr, N, HID_F / 64);
  ushort_t* h2 = U2;
  k_gather2<<<gblocks, 256, 0, stream>>>(t2, h2, rowptr, csr, dinv, b2, N);

  // layer 3: GEMM 256->64 (dinv row) -> t3; gather (+dinv, b3) + L2-normalize -> out
  ushort_t* t3 = U1;
  k_mfma_gemm<HID_F, false><<<(MT * (EMB_F / 64) + 3) / 4, 256, 0, stream>>>(
      h2, W3t, t3, dinv, nullptr, N, EMB_F / 64);
  k_gather3<<<gblocks, 256, 0, stream>>>(t3, out, rowptr, csr, dinv, b3, N);
}

// Round 5
// 473.033 us; speedup vs baseline: 20.9518x; 1.2565x over previous
//
#include <hip/hip_runtime.h>
#include <cstddef>
#include <cstdint>

constexpr int IN_F  = 128;
constexpr int HID_F = 256;
constexpr int EMB_F = 64;

typedef float  f32x4  __attribute__((ext_vector_type(4)));
typedef short  bf16x8 __attribute__((ext_vector_type(8)));
typedef unsigned short ushort_t;
typedef ushort_t u16x4 __attribute__((ext_vector_type(4)));
typedef ushort_t u16x2 __attribute__((ext_vector_type(2)));

__device__ inline float bf2f(ushort_t u) {
  union { unsigned i; float f; } c; c.i = ((unsigned)u) << 16; return c.f;
}
__device__ inline ushort_t f2bf(float f) {  // round-to-nearest-even
  union { float f; unsigned i; } c; c.f = f;
  unsigned r = c.i + 0x7FFFu + ((c.i >> 16) & 1u);
  return (ushort_t)(r >> 16);
}

// ---------------- setup: three weight transposes to bf16 ----------------

__global__ void k_setup(const float* __restrict__ W1, const float* __restrict__ W2,
                        const float* __restrict__ W3,
                        ushort_t* __restrict__ W1t, ushort_t* __restrict__ W2t,
                        ushort_t* __restrict__ W3t) {
  constexpr int c1 = IN_F * HID_F;
  constexpr int c2 = c1 + HID_F * HID_F;
  constexpr int c3 = c2 + HID_F * EMB_F;
  int i = blockIdx.x * blockDim.x + threadIdx.x;
  if (i < c1) {
    int k = i / HID_F, nn = i - k * HID_F;
    W1t[(size_t)nn * IN_F + k] = f2bf(W1[i]);
  } else if (i < c2) {
    int j = i - c1;
    int k = j / HID_F, nn = j - k * HID_F;
    W2t[(size_t)nn * HID_F + k] = f2bf(W2[j]);
  } else if (i < c3) {
    int j = i - c2;
    int k = j / EMB_F, nn = j - k * EMB_F;
    W3t[(size_t)nn * HID_F + k] = f2bf(W3[j]);
  }
}

// ---------------- bucketed CSR build ----------------
// bucket = dst >> 8 (256 nodes/bucket); pack = ((dst&255)<<17) | src  (src < 2^17)

constexpr int NBKT = 512;       // array size; used buckets = ceil(N/256)
constexpr int CHUNK = 16384;    // edges per block in hist/passA

__global__ __launch_bounds__(512) void k_hist(const int* __restrict__ dst,
                                              int* __restrict__ ghist, int e) {
  __shared__ int cnt[NBKT];
  cnt[threadIdx.x] = 0;
  __syncthreads();
  int i0 = blockIdx.x * CHUNK;
  int i1 = min(e, i0 + CHUNK);
  for (int i = i0 + threadIdx.x; i < i1; i += 512)
    atomicAdd(&cnt[dst[i] >> 8], 1);
  __syncthreads();
  int c = cnt[threadIdx.x];
  if (c > 0) atomicAdd(&ghist[threadIdx.x], c);
}

// exclusive scan of ghist -> bstart; gcursor = bstart
__global__ __launch_bounds__(512) void k_bscan(const int* __restrict__ ghist,
                                               int* __restrict__ bstart,
                                               int* __restrict__ gcursor) {
  __shared__ int s[NBKT];
  int v = ghist[threadIdx.x];
  s[threadIdx.x] = v;
  __syncthreads();
#pragma unroll
  for (int off = 1; off < NBKT; off <<= 1) {
    int t = (threadIdx.x >= off) ? s[threadIdx.x - off] : 0;
    __syncthreads();
    s[threadIdx.x] += t;
    __syncthreads();
  }
  int ex = s[threadIdx.x] - v;
  bstart[threadIdx.x] = ex;
  gcursor[threadIdx.x] = ex;
}

__global__ __launch_bounds__(512) void k_passA(const int* __restrict__ src,
                                               const int* __restrict__ dst,
                                               int* __restrict__ gcursor,
                                               unsigned* __restrict__ staged, int e) {
  __shared__ int cnt[NBKT];
  __shared__ int base[NBKT];
  cnt[threadIdx.x] = 0;
  __syncthreads();
  int i0 = blockIdx.x * CHUNK;
  int i1 = min(e, i0 + CHUNK);
  for (int i = i0 + threadIdx.x; i < i1; i += 512)
    atomicAdd(&cnt[dst[i] >> 8], 1);
  __syncthreads();
  int c = cnt[threadIdx.x];
  base[threadIdx.x] = (c > 0) ? atomicAdd(&gcursor[threadIdx.x], c) : 0;
  cnt[threadIdx.x] = 0;  // reuse as local cursor
  __syncthreads();
  for (int i = i0 + threadIdx.x; i < i1; i += 512) {
    int d = dst[i];
    int b = d >> 8;
    int lp = atomicAdd(&cnt[b], 1);
    staged[base[b] + lp] = ((unsigned)(d & 255) << 17) | (unsigned)src[i];
  }
}

// per bucket: in-degree count -> edgedeg, dinv
__global__ __launch_bounds__(256) void k_B1(const unsigned* __restrict__ staged,
                                            const int* __restrict__ bstart,
                                            const int* __restrict__ ghist,
                                            int* __restrict__ edgedeg,
                                            float* __restrict__ dinv, int n) {
  __shared__ int cnt[256];
  cnt[threadIdx.x] = 0;
  __syncthreads();
  int b = blockIdx.x;
  int beg = bstart[b], end = beg + ghist[b];
  for (int i = beg + threadIdx.x; i < end; i += 256)
    atomicAdd(&cnt[staged[i] >> 17], 1);
  __syncthreads();
  int node = (b << 8) + threadIdx.x;
  if (node < n) {
    int c = cnt[threadIdx.x];
    edgedeg[node] = c;
    dinv[node] = rsqrtf((float)(c + 1));
  }
}

// per bucket: place srcs into csr via rowptr + LDS cursors (dense single-block writes)
__global__ __launch_bounds__(256) void k_B2(const unsigned* __restrict__ staged,
                                            const int* __restrict__ bstart,
                                            const int* __restrict__ ghist,
                                            const int* __restrict__ rowptr,
                                            int* __restrict__ csr, int n) {
  __shared__ int cur[256];
  cur[threadIdx.x] = 0;
  __syncthreads();
  int b = blockIdx.x;
  int beg = bstart[b], end = beg + ghist[b];
  int nb0 = b << 8;
  for (int i = beg + threadIdx.x; i < end; i += 256) {
    unsigned p = staged[i];
    int l = (int)(p >> 17);
    int s = (int)(p & 0x1FFFFu);
    int pos = rowptr[nb0 + l] + atomicAdd(&cur[l], 1);
    csr[pos] = s;
  }
}

// ---------------- scan of edgedeg -> rowptr ----------------

__global__ void k_scan1(const int* __restrict__ edgedeg, int* __restrict__ rowptr,
                        int* __restrict__ bsum, int n) {
  __shared__ int s[256];
  int i = blockIdx.x * 256 + threadIdx.x;
  int v = (i < n) ? edgedeg[i] : 0;
  s[threadIdx.x] = v;
  __syncthreads();
#pragma unroll
  for (int off = 1; off < 256; off <<= 1) {
    int t = (threadIdx.x >= off) ? s[threadIdx.x - off] : 0;
    __syncthreads();
    s[threadIdx.x] += t;
    __syncthreads();
  }
  if (i < n) rowptr[i] = s[threadIdx.x] - v;
  if (threadIdx.x == 255) bsum[blockIdx.x] = s[255];
}

__global__ void k_scan2(int* __restrict__ bsum, int nb) {  // nb <= 512
  __shared__ int s[512];
  int v = (threadIdx.x < nb) ? bsum[threadIdx.x] : 0;
  s[threadIdx.x] = v;
  __syncthreads();
#pragma unroll
  for (int off = 1; off < 512; off <<= 1) {
    int t = (threadIdx.x >= off) ? s[threadIdx.x - off] : 0;
    __syncthreads();
    s[threadIdx.x] += t;
    __syncthreads();
  }
  if (threadIdx.x < nb) bsum[threadIdx.x] = s[threadIdx.x] - v;
}

__global__ void k_scan3(int* __restrict__ rowptr, const int* __restrict__ bsum,
                        int n, int e) {
  int i = blockIdx.x * blockDim.x + threadIdx.x;
  if (i < n) rowptr[i] += bsum[i >> 8];
  else if (i == n) rowptr[n] = e;
}

// ---------------- xb = bf16(x * dinv[row]) ----------------

__global__ void k_xconv(const float* __restrict__ x, const float* __restrict__ dinv,
                        ushort_t* __restrict__ xb, int n4 /* N*32 */) {
  int i = blockIdx.x * blockDim.x + threadIdx.x;
  if (i >= n4) return;
  float s = dinv[i >> 5];
  float4 v = reinterpret_cast<const float4*>(x)[i];
  u16x4 o;
  o[0] = f2bf(v.x * s); o[1] = f2bf(v.y * s); o[2] = f2bf(v.z * s); o[3] = f2bf(v.w * s);
  reinterpret_cast<u16x4*>(xb)[i] = o;
}

// ---------------- gathers (one wave per node, fp32 accumulate, 4-edge unroll) ----------------

__global__ __launch_bounds__(256) void k_gather1(
    const ushort_t* __restrict__ t, ushort_t* __restrict__ outp,
    const int* __restrict__ rowptr, const int* __restrict__ csr, int n) {
  int wid = (blockIdx.x * blockDim.x + threadIdx.x) >> 6;
  int lane = threadIdx.x & 63;
  if (wid >= n) return;
  float a0, a1;
  {
    u16x2 v = *reinterpret_cast<const u16x2*>(t + (size_t)wid * IN_F + lane * 2);
    a0 = bf2f(v[0]); a1 = bf2f(v[1]);
  }
  int beg = rowptr[wid], end = rowptr[wid + 1];
  int j = beg;
  for (; j + 3 < end; j += 4) {
    int s0 = csr[j], s1 = csr[j + 1], s2 = csr[j + 2], s3 = csr[j + 3];
    u16x2 v0 = *reinterpret_cast<const u16x2*>(t + (size_t)s0 * IN_F + lane * 2);
    u16x2 v1 = *reinterpret_cast<const u16x2*>(t + (size_t)s1 * IN_F + lane * 2);
    u16x2 v2 = *reinterpret_cast<const u16x2*>(t + (size_t)s2 * IN_F + lane * 2);
    u16x2 v3 = *reinterpret_cast<const u16x2*>(t + (size_t)s3 * IN_F + lane * 2);
    a0 += bf2f(v0[0]); a1 += bf2f(v0[1]);
    a0 += bf2f(v1[0]); a1 += bf2f(v1[1]);
    a0 += bf2f(v2[0]); a1 += bf2f(v2[1]);
    a0 += bf2f(v3[0]); a1 += bf2f(v3[1]);
  }
  for (; j < end; ++j) {
    int s0 = csr[j];
    u16x2 v0 = *reinterpret_cast<const u16x2*>(t + (size_t)s0 * IN_F + lane * 2);
    a0 += bf2f(v0[0]); a1 += bf2f(v0[1]);
  }
  u16x2 o; o[0] = f2bf(a0); o[1] = f2bf(a1);
  *reinterpret_cast<u16x2*>(outp + (size_t)wid * IN_F + lane * 2) = o;
}

__global__ __launch_bounds__(256) void k_gather2(
    const ushort_t* __restrict__ t, ushort_t* __restrict__ outp,
    const int* __restrict__ rowptr, const int* __restrict__ csr,
    const float* __restrict__ dinv, const float* __restrict__ bias, int n) {
  int wid = (blockIdx.x * blockDim.x + threadIdx.x) >> 6;
  int lane = threadIdx.x & 63;
  if (wid >= n) return;
  float acc[4];
  {
    u16x4 v = *reinterpret_cast<const u16x4*>(t + (size_t)wid * HID_F + lane * 4);
#pragma unroll
    for (int k = 0; k < 4; ++k) acc[k] = bf2f(v[k]);
  }
  int beg = rowptr[wid], end = rowptr[wid + 1];
  int j = beg;
  for (; j + 3 < end; j += 4) {
    int s0 = csr[j], s1 = csr[j + 1], s2 = csr[j + 2], s3 = csr[j + 3];
    u16x4 v0 = *reinterpret_cast<const u16x4*>(t + (size_t)s0 * HID_F + lane * 4);
    u16x4 v1 = *reinterpret_cast<const u16x4*>(t + (size_t)s1 * HID_F + lane * 4);
    u16x4 v2 = *reinterpret_cast<const u16x4*>(t + (size_t)s2 * HID_F + lane * 4);
    u16x4 v3 = *reinterpret_cast<const u16x4*>(t + (size_t)s3 * HID_F + lane * 4);
#pragma unroll
    for (int k = 0; k < 4; ++k) acc[k] += bf2f(v0[k]);
#pragma unroll
    for (int k = 0; k < 4; ++k) acc[k] += bf2f(v1[k]);
#pragma unroll
    for (int k = 0; k < 4; ++k) acc[k] += bf2f(v2[k]);
#pragma unroll
    for (int k = 0; k < 4; ++k) acc[k] += bf2f(v3[k]);
  }
  for (; j < end; ++j) {
    int s0 = csr[j];
    u16x4 v0 = *reinterpret_cast<const u16x4*>(t + (size_t)s0 * HID_F + lane * 4);
#pragma unroll
    for (int k = 0; k < 4; ++k) acc[k] += bf2f(v0[k]);
  }
  float s = dinv[wid];
  int c = lane * 4;
  u16x4 o;
#pragma unroll
  for (int k = 0; k < 4; ++k) o[k] = f2bf(fmaxf(fmaf(acc[k], s, bias[c + k]), 0.f));
  *reinterpret_cast<u16x4*>(outp + (size_t)wid * HID_F + lane * 4) = o;
}

__global__ __launch_bounds__(256) void k_gather3(
    const ushort_t* __restrict__ t, float* __restrict__ outp,
    const int* __restrict__ rowptr, const int* __restrict__ csr,
    const float* __restrict__ dinv, const float* __restrict__ b3, int n) {
  int wid = (blockIdx.x * blockDim.x + threadIdx.x) >> 6;
  int lane = threadIdx.x & 63;
  if (wid >= n) return;
  float a = bf2f(t[(size_t)wid * EMB_F + lane]);
  int beg = rowptr[wid], end = rowptr[wid + 1];
  int j = beg;
  for (; j + 3 < end; j += 4) {
    int s0 = csr[j], s1 = csr[j + 1], s2 = csr[j + 2], s3 = csr[j + 3];
    float v0 = bf2f(t[(size_t)s0 * EMB_F + lane]);
    float v1 = bf2f(t[(size_t)s1 * EMB_F + lane]);
    float v2 = bf2f(t[(size_t)s2 * EMB_F + lane]);
    float v3 = bf2f(t[(size_t)s3 * EMB_F + lane]);
    a += v0; a += v1; a += v2; a += v3;
  }
  for (; j < end; ++j) a += bf2f(t[(size_t)csr[j] * EMB_F + lane]);
  float v = fmaf(a, dinv[wid], b3[lane]);
  float ss = v * v;
#pragma unroll
  for (int off = 32; off > 0; off >>= 1) ss += __shfl_xor(ss, off);
  float nrm = sqrtf(ss);
  outp[(size_t)wid * EMB_F + lane] = v / fmaxf(nrm, 1e-12f);
}

// ---------------- LDS-free MFMA GEMM ----------------
// C[M][N] = dinv[row] * (A[M][K] @ Wt[N][K]^T)  (+bias, relu if RELU)
// wave-tile 64x64; mfma_f32_16x16x32_bf16; C/D: col=lane&15, row=(lane>>4)*4+reg

template<int K, bool RELU>
__global__ __launch_bounds__(256) void k_mfma_gemm(
    const ushort_t* __restrict__ A, const ushort_t* __restrict__ Wt,
    ushort_t* __restrict__ C,
    const float* __restrict__ dinv, const float* __restrict__ bias,
    int M, int NT /* N/64 */) {
  int w = blockIdx.x * 4 + (threadIdx.x >> 6);
  int lane = threadIdx.x & 63;
  int mt = w / NT, nt = w - mt * NT;
  int mbase = mt * 64, nbase = nt * 64;
  if (mbase >= M) return;
  const int lrow = lane & 15;
  const int lk = (lane >> 4) * 8;
  const int N = NT * 64;

  int rows[4];
#pragma unroll
  for (int i = 0; i < 4; ++i) {
    int r = mbase + i * 16 + lrow;
    rows[i] = (r < M) ? r : (M - 1);  // clamp loads; stores guarded
  }

  f32x4 acc[4][4] = {};

#pragma unroll 2
  for (int k0 = 0; k0 < K; k0 += 32) {
    bf16x8 a[4], b[4];
#pragma unroll
    for (int i = 0; i < 4; ++i)
      a[i] = *reinterpret_cast<const bf16x8*>(A + (size_t)rows[i] * K + k0 + lk);
#pragma unroll
    for (int n = 0; n < 4; ++n)
      b[n] = *reinterpret_cast<const bf16x8*>(Wt + (size_t)(nbase + n * 16 + lrow) * K + k0 + lk);
#pragma unroll
    for (int i = 0; i < 4; ++i)
#pragma unroll
      for (int n = 0; n < 4; ++n)
        acc[i][n] = __builtin_amdgcn_mfma_f32_16x16x32_bf16(a[i], b[n], acc[i][n], 0, 0, 0);
  }

#pragma unroll
  for (int i = 0; i < 4; ++i) {
    int growb = mbase + i * 16 + (lane >> 4) * 4;
#pragma unroll
    for (int r = 0; r < 4; ++r) {
      int grow = growb + r;
      if (grow >= M) continue;
      float s = dinv[grow];
#pragma unroll
      for (int n = 0; n < 4; ++n) {
        int gcol = nbase + n * 16 + (lane & 15);
        float v = acc[i][n][r] * s;
        if (RELU) v = fmaxf(v + bias[gcol], 0.f);
        C[(size_t)grow * N + gcol] = f2bf(v);
      }
    }
  }
}

// ---------------- launch ----------------

extern "C" void kernel_launch(void* const* d_in, const int* in_sizes, int n_in,
                              void* d_out, int out_size, void* d_ws, size_t ws_size,
                              hipStream_t stream) {
  const float* x  = (const float*)d_in[0];
  const int*   ei = (const int*)d_in[1];
  const float* W1 = (const float*)d_in[2];
  const float* b1 = (const float*)d_in[3];
  const float* W2 = (const float*)d_in[4];
  const float* b2 = (const float*)d_in[5];
  const float* W3 = (const float*)d_in[6];
  const float* b3 = (const float*)d_in[7];
  const int N = in_sizes[0] / IN_F;
  const int E = in_sizes[1] / 2;
  const int* src = ei;
  const int* dst = ei + E;

  char* m = (char*)d_ws;
  auto alloc = [&](size_t bytes) { char* p = m; m += (bytes + 255) & ~(size_t)255; return p; };
  ushort_t* U1  = (ushort_t*)alloc((size_t)N * HID_F * 2);  // N x 256 bf16
  ushort_t* U2  = (ushort_t*)alloc((size_t)N * HID_F * 2);
  ushort_t* W1t = (ushort_t*)alloc((size_t)IN_F * HID_F * 2);
  ushort_t* W2t = (ushort_t*)alloc((size_t)HID_F * HID_F * 2);
  ushort_t* W3t = (ushort_t*)alloc((size_t)HID_F * EMB_F * 2);
  int*      edgedeg = (int*)alloc((size_t)N * 4);
  float*    dinv    = (float*)alloc((size_t)N * 4);
  int*      rowptr  = (int*)alloc((size_t)(N + 1) * 4);
  int*      bsum    = (int*)alloc(512 * 4);
  int*      ghist   = (int*)alloc(NBKT * 4);
  int*      bstart  = (int*)alloc(NBKT * 4);
  int*      gcursor = (int*)alloc(NBKT * 4);
  unsigned* staged  = (unsigned*)alloc((size_t)E * 4);
  int*      csr     = (int*)alloc((size_t)E * 4);
  float*    out     = (float*)d_out;

  const int nb = (N + 255) / 256;        // scan blocks (<= 512)
  const int nbkt_used = (N + 255) / 256; // buckets (dst>>8)
  const int echunks = (E + CHUNK - 1) / CHUNK;
  constexpr int SETUP_W = IN_F * HID_F + HID_F * HID_F + HID_F * EMB_F;

  // weights -> bf16 transposed
  k_setup<<<(SETUP_W + 255) / 256, 256, 0, stream>>>(W1, W2, W3, W1t, W2t, W3t);

  // bucketed CSR build
  hipMemsetAsync(ghist, 0, NBKT * 4, stream);
  k_hist <<<echunks, 512, 0, stream>>>(dst, ghist, E);
  k_bscan<<<1, NBKT, 0, stream>>>(ghist, bstart, gcursor);
  k_passA<<<echunks, 512, 0, stream>>>(src, dst, gcursor, staged, E);
  k_B1   <<<nbkt_used, 256, 0, stream>>>(staged, bstart, ghist, edgedeg, dinv, N);

  // scan edgedeg -> rowptr
  k_scan1<<<nb, 256, 0, stream>>>(edgedeg, rowptr, bsum, N);
  k_scan2<<<1, 512, 0, stream>>>(bsum, nb);
  k_scan3<<<(N + 1 + 255) / 256, 256, 0, stream>>>(rowptr, bsum, N, E);

  // xb = bf16(x * dinv)  (aliased into U2; dead before gemm1 writes U2)
  ushort_t* xb = U2;
  k_xconv<<<((N * 32) + 255) / 256, 256, 0, stream>>>(x, dinv, xb, N * 32);

  // place edges into csr
  k_B2<<<nbkt_used, 256, 0, stream>>>(staged, bstart, ghist, rowptr, csr, N);

  const int gblocks = (N + 3) / 4;  // 4 waves per block, 1 node per wave
  const int MT = (N + 63) / 64;

  // layer 1: gather xb -> aggX bf16 [N,128]; GEMM 128->256 (+dinv row, +b1, relu)
  ushort_t* aggX = U1;
  k_gather1<<<gblocks, 256, 0, stream>>>(xb, aggX, rowptr, csr, N);
  ushort_t* h1 = U2;
  k_mfma_gemm<IN_F, true><<<(MT * (HID_F / 64) + 3) / 4, 256, 0, stream>>>(
      aggX, W1t, h1, dinv, b1, N, HID_F / 64);

  // layer 2: GEMM 256->256 (dinv row) -> t2; gather (+dinv, b2, relu) -> h2
  ushort_t* t2 = U1;
  k_mfma_gemm<HID_F, false><<<(MT * (HID_F / 64) + 3) / 4, 256, 0, stream>>>(
      h1, W2t, t2, dinv, nullptr, N, HID_F / 64);
  ushort_t* h2 = U2;
  k_gather2<<<gblocks, 256, 0, stream>>>(t2, h2, rowptr, csr, dinv, b2, N);

  // layer 3: GEMM 256->64 (dinv row) -> t3; gather (+dinv, b3) + L2-normalize -> out
  ushort_t* t3 = U1;
  k_mfma_gemm<HID_F, false><<<(MT * (EMB_F / 64) + 3) / 4, 256, 0, stream>>>(
      h2, W3t, t3, dinv, nullptr, N, EMB_F / 64);
  k_gather3<<<gblocks, 256, 0, stream>>>(t3, out, rowptr, csr, dinv, b3, N);
}

// Round 6
// 469.421 us; speedup vs baseline: 21.1130x; 1.0077x over previous
//
#include <hip/hip_runtime.h>
#include <cstddef>
#include <cstdint>

constexpr int IN_F  = 128;
constexpr int HID_F = 256;
constexpr int EMB_F = 64;

typedef float  f32x4  __attribute__((ext_vector_type(4)));
typedef short  bf16x8 __attribute__((ext_vector_type(8)));
typedef unsigned short ushort_t;
typedef ushort_t u16x8 __attribute__((ext_vector_type(8)));
typedef ushort_t u16x4 __attribute__((ext_vector_type(4)));

__device__ inline float bf2f(ushort_t u) {
  union { unsigned i; float f; } c; c.i = ((unsigned)u) << 16; return c.f;
}
__device__ inline ushort_t f2bf(float f) {  // round-to-nearest-even
  union { float f; unsigned i; } c; c.f = f;
  unsigned r = c.i + 0x7FFFu + ((c.i >> 16) & 1u);
  return (ushort_t)(r >> 16);
}

constexpr int NBKT = 512;       // bucket array size; used = ceil(N/256)
constexpr int CHUNK = 16384;    // edges per block in hist/passA

// ---------------- setup: weight transposes to bf16 + ghist zero ----------------

__global__ void k_setup(const float* __restrict__ W1, const float* __restrict__ W2,
                        const float* __restrict__ W3,
                        ushort_t* __restrict__ W1t, ushort_t* __restrict__ W2t,
                        ushort_t* __restrict__ W3t, int* __restrict__ ghist) {
  constexpr int c1 = IN_F * HID_F;
  constexpr int c2 = c1 + HID_F * HID_F;
  constexpr int c3 = c2 + HID_F * EMB_F;
  int i = blockIdx.x * blockDim.x + threadIdx.x;
  if (i < c1) {
    int k = i / HID_F, nn = i - k * HID_F;
    W1t[(size_t)nn * IN_F + k] = f2bf(W1[i]);
  } else if (i < c2) {
    int j = i - c1;
    int k = j / HID_F, nn = j - k * HID_F;
    W2t[(size_t)nn * HID_F + k] = f2bf(W2[j]);
  } else if (i < c3) {
    int j = i - c2;
    int k = j / EMB_F, nn = j - k * EMB_F;
    W3t[(size_t)nn * HID_F + k] = f2bf(W3[j]);
  } else if (i - c3 < NBKT) {
    ghist[i - c3] = 0;
  }
}

// ---------------- bucketed CSR build ----------------
// bucket = dst >> 8; pack = ((dst&255)<<17) | src  (src < 2^17)

__global__ __launch_bounds__(512) void k_hist(const int* __restrict__ dst,
                                              int* __restrict__ ghist, int e) {
  __shared__ int cnt[NBKT];
  cnt[threadIdx.x] = 0;
  __syncthreads();
  int i0 = blockIdx.x * CHUNK;
  int i1 = min(e, i0 + CHUNK);
  for (int i = i0 + threadIdx.x; i < i1; i += 512)
    atomicAdd(&cnt[dst[i] >> 8], 1);
  __syncthreads();
  int c = cnt[threadIdx.x];
  if (c > 0) atomicAdd(&ghist[threadIdx.x], c);
}

__global__ __launch_bounds__(512) void k_bscan(const int* __restrict__ ghist,
                                               int* __restrict__ bstart,
                                               int* __restrict__ gcursor) {
  __shared__ int s[NBKT];
  int v = ghist[threadIdx.x];
  s[threadIdx.x] = v;
  __syncthreads();
#pragma unroll
  for (int off = 1; off < NBKT; off <<= 1) {
    int t = (threadIdx.x >= off) ? s[threadIdx.x - off] : 0;
    __syncthreads();
    s[threadIdx.x] += t;
    __syncthreads();
  }
  int ex = s[threadIdx.x] - v;
  bstart[threadIdx.x] = ex;
  gcursor[threadIdx.x] = ex;
}

__global__ __launch_bounds__(512) void k_passA(const int* __restrict__ src,
                                               const int* __restrict__ dst,
                                               int* __restrict__ gcursor,
                                               unsigned* __restrict__ staged, int e) {
  __shared__ int cnt[NBKT];
  __shared__ int base[NBKT];
  cnt[threadIdx.x] = 0;
  __syncthreads();
  int i0 = blockIdx.x * CHUNK;
  int i1 = min(e, i0 + CHUNK);
  for (int i = i0 + threadIdx.x; i < i1; i += 512)
    atomicAdd(&cnt[dst[i] >> 8], 1);
  __syncthreads();
  int c = cnt[threadIdx.x];
  base[threadIdx.x] = (c > 0) ? atomicAdd(&gcursor[threadIdx.x], c) : 0;
  cnt[threadIdx.x] = 0;  // reuse as local cursor
  __syncthreads();
  for (int i = i0 + threadIdx.x; i < i1; i += 512) {
    int d = dst[i];
    int b = d >> 8;
    int lp = atomicAdd(&cnt[b], 1);
    staged[base[b] + lp] = ((unsigned)(d & 255) << 17) | (unsigned)src[i];
  }
}

// per bucket: in-degree count -> dinv; in-block exclusive scan -> rowptr partial + bsum
__global__ __launch_bounds__(256) void k_B1scan(const unsigned* __restrict__ staged,
                                                const int* __restrict__ bstart,
                                                const int* __restrict__ ghist,
                                                float* __restrict__ dinv,
                                                int* __restrict__ rowptr,
                                                int* __restrict__ bsum, int n) {
  __shared__ int cnt[256];
  __shared__ int s[256];
  cnt[threadIdx.x] = 0;
  __syncthreads();
  int b = blockIdx.x;
  int beg = bstart[b], end = beg + ghist[b];
  for (int i = beg + threadIdx.x; i < end; i += 256)
    atomicAdd(&cnt[staged[i] >> 17], 1);
  __syncthreads();
  int node = (b << 8) + threadIdx.x;
  int v = (node < n) ? cnt[threadIdx.x] : 0;
  if (node < n) dinv[node] = rsqrtf((float)(v + 1));
  s[threadIdx.x] = v;
  __syncthreads();
#pragma unroll
  for (int off = 1; off < 256; off <<= 1) {
    int t = (threadIdx.x >= off) ? s[threadIdx.x - off] : 0;
    __syncthreads();
    s[threadIdx.x] += t;
    __syncthreads();
  }
  if (node < n) rowptr[node] = s[threadIdx.x] - v;
  if (threadIdx.x == 255) bsum[b] = s[255];
}

__global__ void k_scan2(int* __restrict__ bsum, int nb) {  // nb <= 512
  __shared__ int s[512];
  int v = (threadIdx.x < nb) ? bsum[threadIdx.x] : 0;
  s[threadIdx.x] = v;
  __syncthreads();
#pragma unroll
  for (int off = 1; off < 512; off <<= 1) {
    int t = (threadIdx.x >= off) ? s[threadIdx.x - off] : 0;
    __syncthreads();
    s[threadIdx.x] += t;
    __syncthreads();
  }
  if (threadIdx.x < nb) bsum[threadIdx.x] = s[threadIdx.x] - v;
}

// fused: rowptr finalize + xb = bf16(x * dinv[row])
__global__ void k_scan3x(int* __restrict__ rowptr, const int* __restrict__ bsum,
                         const float* __restrict__ x, const float* __restrict__ dinv,
                         ushort_t* __restrict__ xb, int n, int e) {
  int i = blockIdx.x * blockDim.x + threadIdx.x;
  int n32 = n * 32;
  if (i < n32) {
    float s = dinv[i >> 5];
    float4 v = reinterpret_cast<const float4*>(x)[i];
    u16x4 o;
    o[0] = f2bf(v.x * s); o[1] = f2bf(v.y * s); o[2] = f2bf(v.z * s); o[3] = f2bf(v.w * s);
    reinterpret_cast<u16x4*>(xb)[i] = o;
  } else {
    int j = i - n32;
    if (j < n) rowptr[j] += bsum[j >> 8];
    else if (j == n) rowptr[n] = e;
  }
}

// per bucket: place srcs into csr via rowptr + LDS cursors
__global__ __launch_bounds__(256) void k_B2(const unsigned* __restrict__ staged,
                                            const int* __restrict__ bstart,
                                            const int* __restrict__ ghist,
                                            const int* __restrict__ rowptr,
                                            int* __restrict__ csr, int n) {
  __shared__ int cur[256];
  cur[threadIdx.x] = 0;
  __syncthreads();
  int b = blockIdx.x;
  int beg = bstart[b], end = beg + ghist[b];
  int nb0 = b << 8;
  for (int i = beg + threadIdx.x; i < end; i += 256) {
    unsigned p = staged[i];
    int l = (int)(p >> 17);
    int s = (int)(p & 0x1FFFFu);
    int pos = rowptr[nb0 + l] + atomicAdd(&cur[l], 1);
    csr[pos] = s;
  }
}

// ---------------- gathers: one wave per node, lane-group row split ----------------
// item 0 = self row, items 1.. = csr edges. fp32 accumulate, shfl combine.

// layer 1: F=128, row=256B = 32 lanes x 8B; 2 items/step, 2-unroll (4 rows in flight)
__global__ __launch_bounds__(256) void k_gather1(
    const ushort_t* __restrict__ t, ushort_t* __restrict__ outp,
    const int* __restrict__ rowptr, const int* __restrict__ csr, int n) {
  int wid = (blockIdx.x * blockDim.x + threadIdx.x) >> 6;
  int lane = threadIdx.x & 63;
  if (wid >= n) return;
  const int half = lane >> 5, sub = lane & 31;
  const int coff = sub * 4;
  int beg = rowptr[wid], end = rowptr[wid + 1];
  int nitems = end - beg + 1;
  float acc[4] = {};
  int i = 0;
  for (; i + 3 < nitems; i += 4) {
    int i0 = i + half, i1 = i + 2 + half;
    int r0 = (i0 == 0) ? wid : csr[beg + i0 - 1];
    int r1 = csr[beg + i1 - 1];
    u16x4 v0 = *reinterpret_cast<const u16x4*>(t + (size_t)r0 * IN_F + coff);
    u16x4 v1 = *reinterpret_cast<const u16x4*>(t + (size_t)r1 * IN_F + coff);
#pragma unroll
    for (int k = 0; k < 4; ++k) acc[k] += bf2f(v0[k]);
#pragma unroll
    for (int k = 0; k < 4; ++k) acc[k] += bf2f(v1[k]);
  }
  for (; i < nitems; i += 2) {
    int i0 = i + half;
    if (i0 < nitems) {
      int r0 = (i0 == 0) ? wid : csr[beg + i0 - 1];
      u16x4 v0 = *reinterpret_cast<const u16x4*>(t + (size_t)r0 * IN_F + coff);
#pragma unroll
      for (int k = 0; k < 4; ++k) acc[k] += bf2f(v0[k]);
    }
  }
#pragma unroll
  for (int k = 0; k < 4; ++k) acc[k] += __shfl_xor(acc[k], 32);
  if (half == 0) {
    u16x4 o;
#pragma unroll
    for (int k = 0; k < 4; ++k) o[k] = f2bf(acc[k]);
    *reinterpret_cast<u16x4*>(outp + (size_t)wid * IN_F + coff) = o;
  }
}

// layer 2: F=256, row=512B = 32 lanes x 16B; 2 items/step, 2-unroll
__global__ __launch_bounds__(256) void k_gather2(
    const ushort_t* __restrict__ t, ushort_t* __restrict__ outp,
    const int* __restrict__ rowptr, const int* __restrict__ csr,
    const float* __restrict__ dinv, const float* __restrict__ bias, int n) {
  int wid = (blockIdx.x * blockDim.x + threadIdx.x) >> 6;
  int lane = threadIdx.x & 63;
  if (wid >= n) return;
  const int half = lane >> 5, sub = lane & 31;
  const int coff = sub * 8;
  int beg = rowptr[wid], end = rowptr[wid + 1];
  int nitems = end - beg + 1;
  float acc[8] = {};
  int i = 0;
  for (; i + 3 < nitems; i += 4) {
    int i0 = i + half, i1 = i + 2 + half;
    int r0 = (i0 == 0) ? wid : csr[beg + i0 - 1];
    int r1 = csr[beg + i1 - 1];
    u16x8 v0 = *reinterpret_cast<const u16x8*>(t + (size_t)r0 * HID_F + coff);
    u16x8 v1 = *reinterpret_cast<const u16x8*>(t + (size_t)r1 * HID_F + coff);
#pragma unroll
    for (int k = 0; k < 8; ++k) acc[k] += bf2f(v0[k]);
#pragma unroll
    for (int k = 0; k < 8; ++k) acc[k] += bf2f(v1[k]);
  }
  for (; i < nitems; i += 2) {
    int i0 = i + half;
    if (i0 < nitems) {
      int r0 = (i0 == 0) ? wid : csr[beg + i0 - 1];
      u16x8 v0 = *reinterpret_cast<const u16x8*>(t + (size_t)r0 * HID_F + coff);
#pragma unroll
      for (int k = 0; k < 8; ++k) acc[k] += bf2f(v0[k]);
    }
  }
#pragma unroll
  for (int k = 0; k < 8; ++k) acc[k] += __shfl_xor(acc[k], 32);
  if (half == 0) {
    float s = dinv[wid];
    u16x8 o;
#pragma unroll
    for (int k = 0; k < 8; ++k) o[k] = f2bf(fmaxf(fmaf(acc[k], s, bias[coff + k]), 0.f));
    *reinterpret_cast<u16x8*>(outp + (size_t)wid * HID_F + coff) = o;
  }
}

// layer 3: F=64, row=128B = 16 lanes x 8B; 4 items/step; bias + L2-normalize
__global__ __launch_bounds__(256) void k_gather3(
    const ushort_t* __restrict__ t, float* __restrict__ outp,
    const int* __restrict__ rowptr, const int* __restrict__ csr,
    const float* __restrict__ dinv, const float* __restrict__ b3, int n) {
  int wid = (blockIdx.x * blockDim.x + threadIdx.x) >> 6;
  int lane = threadIdx.x & 63;
  if (wid >= n) return;
  const int q = lane >> 4, sub = lane & 15;
  const int coff = sub * 4;
  int beg = rowptr[wid], end = rowptr[wid + 1];
  int nitems = end - beg + 1;
  float acc[4] = {};
  for (int i = 0; i < nitems; i += 4) {
    int i0 = i + q;
    if (i0 < nitems) {
      int r0 = (i0 == 0) ? wid : csr[beg + i0 - 1];
      u16x4 v0 = *reinterpret_cast<const u16x4*>(t + (size_t)r0 * EMB_F + coff);
#pragma unroll
      for (int k = 0; k < 4; ++k) acc[k] += bf2f(v0[k]);
    }
  }
#pragma unroll
  for (int k = 0; k < 4; ++k) acc[k] += __shfl_xor(acc[k], 16);
#pragma unroll
  for (int k = 0; k < 4; ++k) acc[k] += __shfl_xor(acc[k], 32);
  // all lanes now hold totals for cols [sub*4, sub*4+4)
  float s = dinv[wid];
  float v[4], ss = 0.f;
#pragma unroll
  for (int k = 0; k < 4; ++k) {
    v[k] = fmaf(acc[k], s, b3[coff + k]);
    ss = fmaf(v[k], v[k], ss);
  }
#pragma unroll
  for (int off = 8; off > 0; off >>= 1) ss += __shfl_xor(ss, off);
  float inv = 1.0f / fmaxf(sqrtf(ss), 1e-12f);
  if (lane < 16) {
    float4 o = make_float4(v[0] * inv, v[1] * inv, v[2] * inv, v[3] * inv);
    *reinterpret_cast<float4*>(outp + (size_t)wid * EMB_F + coff) = o;
  }
}

// ---------------- LDS-free MFMA GEMM ----------------
// C[M][N] = dinv[row] * (A[M][K] @ Wt[N][K]^T)  (+bias, relu if RELU)
// wave-tile 64x64; mfma_f32_16x16x32_bf16; C/D: col=lane&15, row=(lane>>4)*4+reg

template<int K, bool RELU>
__global__ __launch_bounds__(256) void k_mfma_gemm(
    const ushort_t* __restrict__ A, const ushort_t* __restrict__ Wt,
    ushort_t* __restrict__ C,
    const float* __restrict__ dinv, const float* __restrict__ bias,
    int M, int NT /* N/64 */) {
  int w = blockIdx.x * 4 + (threadIdx.x >> 6);
  int lane = threadIdx.x & 63;
  int mt = w / NT, nt = w - mt * NT;
  int mbase = mt * 64, nbase = nt * 64;
  if (mbase >= M) return;
  const int lrow = lane & 15;
  const int lk = (lane >> 4) * 8;
  const int N = NT * 64;

  int rows[4];
#pragma unroll
  for (int i = 0; i < 4; ++i) {
    int r = mbase + i * 16 + lrow;
    rows[i] = (r < M) ? r : (M - 1);  // clamp loads; stores guarded
  }

  f32x4 acc[4][4] = {};

#pragma unroll 2
  for (int k0 = 0; k0 < K; k0 += 32) {
    bf16x8 a[4], b[4];
#pragma unroll
    for (int i = 0; i < 4; ++i)
      a[i] = *reinterpret_cast<const bf16x8*>(A + (size_t)rows[i] * K + k0 + lk);
#pragma unroll
    for (int n = 0; n < 4; ++n)
      b[n] = *reinterpret_cast<const bf16x8*>(Wt + (size_t)(nbase + n * 16 + lrow) * K + k0 + lk);
#pragma unroll
    for (int i = 0; i < 4; ++i)
#pragma unroll
      for (int n = 0; n < 4; ++n)
        acc[i][n] = __builtin_amdgcn_mfma_f32_16x16x32_bf16(a[i], b[n], acc[i][n], 0, 0, 0);
  }

#pragma unroll
  for (int i = 0; i < 4; ++i) {
    int growb = mbase + i * 16 + (lane >> 4) * 4;
#pragma unroll
    for (int r = 0; r < 4; ++r) {
      int grow = growb + r;
      if (grow >= M) continue;
      float s = dinv[grow];
#pragma unroll
      for (int n = 0; n < 4; ++n) {
        int gcol = nbase + n * 16 + (lane & 15);
        float v = acc[i][n][r] * s;
        if (RELU) v = fmaxf(v + bias[gcol], 0.f);
        C[(size_t)grow * N + gcol] = f2bf(v);
      }
    }
  }
}

// ---------------- launch ----------------

extern "C" void kernel_launch(void* const* d_in, const int* in_sizes, int n_in,
                              void* d_out, int out_size, void* d_ws, size_t ws_size,
                              hipStream_t stream) {
  const float* x  = (const float*)d_in[0];
  const int*   ei = (const int*)d_in[1];
  const float* W1 = (const float*)d_in[2];
  const float* b1 = (const float*)d_in[3];
  const float* W2 = (const float*)d_in[4];
  const float* b2 = (const float*)d_in[5];
  const float* W3 = (const float*)d_in[6];
  const float* b3 = (const float*)d_in[7];
  const int N = in_sizes[0] / IN_F;
  const int E = in_sizes[1] / 2;
  const int* src = ei;
  const int* dst = ei + E;

  char* m = (char*)d_ws;
  auto alloc = [&](size_t bytes) { char* p = m; m += (bytes + 255) & ~(size_t)255; return p; };
  ushort_t* U1  = (ushort_t*)alloc((size_t)N * HID_F * 2);  // N x 256 bf16
  ushort_t* U2  = (ushort_t*)alloc((size_t)N * HID_F * 2);
  ushort_t* W1t = (ushort_t*)alloc((size_t)IN_F * HID_F * 2);
  ushort_t* W2t = (ushort_t*)alloc((size_t)HID_F * HID_F * 2);
  ushort_t* W3t = (ushort_t*)alloc((size_t)HID_F * EMB_F * 2);
  float*    dinv    = (float*)alloc((size_t)N * 4);
  int*      rowptr  = (int*)alloc((size_t)(N + 1) * 4);
  int*      bsum    = (int*)alloc(512 * 4);
  int*      ghist   = (int*)alloc(NBKT * 4);
  int*      bstart  = (int*)alloc(NBKT * 4);
  int*      gcursor = (int*)alloc(NBKT * 4);
  unsigned* staged  = (unsigned*)alloc((size_t)E * 4);
  int*      csr     = (int*)alloc((size_t)E * 4);
  float*    out     = (float*)d_out;

  const int nb = (N + 255) / 256;        // buckets / scan blocks (<= 512)
  const int echunks = (E + CHUNK - 1) / CHUNK;
  constexpr int SETUP_W = IN_F * HID_F + HID_F * HID_F + HID_F * EMB_F + NBKT;

  // weights -> bf16 transposed; ghist = 0
  k_setup<<<(SETUP_W + 255) / 256, 256, 0, stream>>>(W1, W2, W3, W1t, W2t, W3t, ghist);

  // bucketed CSR build
  k_hist  <<<echunks, 512, 0, stream>>>(dst, ghist, E);
  k_bscan <<<1, NBKT, 0, stream>>>(ghist, bstart, gcursor);
  k_passA <<<echunks, 512, 0, stream>>>(src, dst, gcursor, staged, E);
  k_B1scan<<<nb, 256, 0, stream>>>(staged, bstart, ghist, dinv, rowptr, bsum, N);
  k_scan2 <<<1, 512, 0, stream>>>(bsum, nb);

  // rowptr finalize + xb = bf16(x * dinv)   (xb aliased into U2)
  ushort_t* xb = U2;
  k_scan3x<<<((N * 32) + N + 1 + 255) / 256, 256, 0, stream>>>(rowptr, bsum, x, dinv, xb, N, E);

  // place edges into csr
  k_B2<<<nb, 256, 0, stream>>>(staged, bstart, ghist, rowptr, csr, N);

  const int gblocks = (N + 3) / 4;  // 4 waves per block, 1 node per wave
  const int MT = (N + 63) / 64;

  // layer 1: gather xb -> aggX bf16 [N,128]; GEMM 128->256 (+dinv row, +b1, relu)
  ushort_t* aggX = U1;
  k_gather1<<<gblocks, 256, 0, stream>>>(xb, aggX, rowptr, csr, N);
  ushort_t* h1 = U2;
  k_mfma_gemm<IN_F, true><<<(MT * (HID_F / 64) + 3) / 4, 256, 0, stream>>>(
      aggX, W1t, h1, dinv, b1, N, HID_F / 64);

  // layer 2: GEMM 256->256 (dinv row) -> t2; gather (+dinv, b2, relu) -> h2
  ushort_t* t2 = U1;
  k_mfma_gemm<HID_F, false><<<(MT * (HID_F / 64) + 3) / 4, 256, 0, stream>>>(
      h1, W2t, t2, dinv, nullptr, N, HID_F / 64);
  ushort_t* h2 = U2;
  k_gather2<<<gblocks, 256, 0, stream>>>(t2, h2, rowptr, csr, dinv, b2, N);

  // layer 3: GEMM 256->64 (dinv row) -> t3; gather (+dinv, b3) + L2-normalize -> out
  ushort_t* t3 = U1;
  k_mfma_gemm<HID_F, false><<<(MT * (EMB_F / 64) + 3) / 4, 256, 0, stream>>>(
      h2, W3t, t3, dinv, nullptr, N, EMB_F / 64);
  k_gather3<<<gblocks, 256, 0, stream>>>(t3, out, rowptr, csr, dinv, b3, N);
}

// Round 7
// 460.357 us; speedup vs baseline: 21.5287x; 1.0197x over previous
//
#include <hip/hip_runtime.h>
#include <cstddef>
#include <cstdint>

constexpr int IN_F  = 128;
constexpr int HID_F = 256;
constexpr int EMB_F = 64;

typedef float  f32x4  __attribute__((ext_vector_type(4)));
typedef short  bf16x8 __attribute__((ext_vector_type(8)));
typedef unsigned short ushort_t;
typedef ushort_t u16x8 __attribute__((ext_vector_type(8)));
typedef ushort_t u16x4 __attribute__((ext_vector_type(4)));

__device__ inline float bf2f(ushort_t u) {
  union { unsigned i; float f; } c; c.i = ((unsigned)u) << 16; return c.f;
}
__device__ inline ushort_t f2bf(float f) {  // round-to-nearest-even
  union { float f; unsigned i; } c; c.f = f;
  unsigned r = c.i + 0x7FFFu + ((c.i >> 16) & 1u);
  return (ushort_t)(r >> 16);
}

constexpr int NBKT = 512;       // bucket array size; used = ceil(N/256)
constexpr int CHUNK = 16384;    // edges per block in hist/passA

// ---------------- setup: weight transposes to bf16 + ghist zero ----------------

__global__ void k_setup(const float* __restrict__ W1, const float* __restrict__ W2,
                        const float* __restrict__ W3,
                        ushort_t* __restrict__ W1t, ushort_t* __restrict__ W2t,
                        ushort_t* __restrict__ W3t, int* __restrict__ ghist) {
  constexpr int c1 = IN_F * HID_F;
  constexpr int c2 = c1 + HID_F * HID_F;
  constexpr int c3 = c2 + HID_F * EMB_F;
  int i = blockIdx.x * blockDim.x + threadIdx.x;
  if (i < c1) {
    int k = i / HID_F, nn = i - k * HID_F;
    W1t[(size_t)nn * IN_F + k] = f2bf(W1[i]);
  } else if (i < c2) {
    int j = i - c1;
    int k = j / HID_F, nn = j - k * HID_F;
    W2t[(size_t)nn * HID_F + k] = f2bf(W2[j]);
  } else if (i < c3) {
    int j = i - c2;
    int k = j / EMB_F, nn = j - k * EMB_F;
    W3t[(size_t)nn * HID_F + k] = f2bf(W3[j]);
  } else if (i - c3 < NBKT) {
    ghist[i - c3] = 0;
  }
}

// ---------------- bucketed CSR build ----------------
// bucket = dst >> 8; pack = ((dst&255)<<17) | src  (src < 2^17)

__global__ __launch_bounds__(512) void k_hist(const int* __restrict__ dst,
                                              int* __restrict__ ghist, int e) {
  __shared__ int cnt[NBKT];
  cnt[threadIdx.x] = 0;
  __syncthreads();
  int i0 = blockIdx.x * CHUNK;
  int i1 = min(e, i0 + CHUNK);
  for (int i = i0 + threadIdx.x; i < i1; i += 512)
    atomicAdd(&cnt[dst[i] >> 8], 1);
  __syncthreads();
  int c = cnt[threadIdx.x];
  if (c > 0) atomicAdd(&ghist[threadIdx.x], c);
}

// exclusive scan of ghist -> bstart (== global rowptr at bucket starts); gcursor = bstart
__global__ __launch_bounds__(512) void k_bscan(const int* __restrict__ ghist,
                                               int* __restrict__ bstart,
                                               int* __restrict__ gcursor) {
  __shared__ int s[NBKT];
  int v = ghist[threadIdx.x];
  s[threadIdx.x] = v;
  __syncthreads();
#pragma unroll
  for (int off = 1; off < NBKT; off <<= 1) {
    int t = (threadIdx.x >= off) ? s[threadIdx.x - off] : 0;
    __syncthreads();
    s[threadIdx.x] += t;
    __syncthreads();
  }
  int ex = s[threadIdx.x] - v;
  bstart[threadIdx.x] = ex;
  gcursor[threadIdx.x] = ex;
}

__global__ __launch_bounds__(512) void k_passA(const int* __restrict__ src,
                                               const int* __restrict__ dst,
                                               int* __restrict__ gcursor,
                                               unsigned* __restrict__ staged, int e) {
  __shared__ int cnt[NBKT];
  __shared__ int base[NBKT];
  cnt[threadIdx.x] = 0;
  __syncthreads();
  int i0 = blockIdx.x * CHUNK;
  int i1 = min(e, i0 + CHUNK);
  for (int i = i0 + threadIdx.x; i < i1; i += 512)
    atomicAdd(&cnt[dst[i] >> 8], 1);
  __syncthreads();
  int c = cnt[threadIdx.x];
  base[threadIdx.x] = (c > 0) ? atomicAdd(&gcursor[threadIdx.x], c) : 0;
  cnt[threadIdx.x] = 0;  // reuse as local cursor
  __syncthreads();
  for (int i = i0 + threadIdx.x; i < i1; i += 512) {
    int d = dst[i];
    int b = d >> 8;
    int lp = atomicAdd(&cnt[b], 1);
    staged[base[b] + lp] = ((unsigned)(d & 255) << 17) | (unsigned)src[i];
  }
}

// Fused per-bucket finalize: count -> dinv + rowptr (bstart[b] + local scan),
// place csr via LDS cursors, convert this bucket's x rows to pre-scaled bf16.
__global__ __launch_bounds__(256) void k_Bfused(
    const unsigned* __restrict__ staged, const int* __restrict__ bstart,
    const int* __restrict__ ghist, const float* __restrict__ x,
    float* __restrict__ dinv, int* __restrict__ rowptr, int* __restrict__ csr,
    ushort_t* __restrict__ xb, int n, int e) {
  __shared__ int cnt[256];
  __shared__ int s[256];
  __shared__ int cur[256];
  __shared__ float dinvL[256];
  const int tid = threadIdx.x;
  const int b = blockIdx.x;
  cnt[tid] = 0;
  __syncthreads();
  const int beg = bstart[b], end = beg + ghist[b];
  for (int i = beg + tid; i < end; i += 256)
    atomicAdd(&cnt[staged[i] >> 17], 1);
  __syncthreads();
  const int node = (b << 8) + tid;
  int v = (node < n) ? cnt[tid] : 0;
  float dv = rsqrtf((float)(v + 1));
  if (node < n) { dinv[node] = dv; }
  dinvL[tid] = dv;
  s[tid] = v;
  __syncthreads();
#pragma unroll
  for (int off = 1; off < 256; off <<= 1) {
    int t = (tid >= off) ? s[tid - off] : 0;
    __syncthreads();
    s[tid] += t;
    __syncthreads();
  }
  int rp = beg + s[tid] - v;  // global rowptr for this node
  if (node < n) rowptr[node] = rp;
  if (b == 0 && tid == 0) rowptr[n] = e;
  cur[tid] = rp;
  __syncthreads();
  // place edges
  for (int i = beg + tid; i < end; i += 256) {
    unsigned p = staged[i];
    int l = (int)(p >> 17);
    int sv = (int)(p & 0x1FFFFu);
    int pos = atomicAdd(&cur[l], 1);
    csr[pos] = sv;
  }
  // xconv for this bucket's nodes: 256 rows x 32 float4
  const int nb0 = b << 8;
  const int rows = min(256, n - nb0);
  const float4* xv = reinterpret_cast<const float4*>(x) + (size_t)nb0 * 32;
  u16x4* xo = reinterpret_cast<u16x4*>(xb) + (size_t)nb0 * 32;
  for (int j = tid; j < rows * 32; j += 256) {
    float sc = dinvL[j >> 5];
    float4 vv = xv[j];
    u16x4 o;
    o[0] = f2bf(vv.x * sc); o[1] = f2bf(vv.y * sc);
    o[2] = f2bf(vv.z * sc); o[3] = f2bf(vv.w * sc);
    xo[j] = o;
  }
}

// ---------------- gathers: one wave per node, lane-group row split ----------------
// item 0 = self row, items 1.. = csr edges. fp32 accumulate, shfl combine.

// layer 1: F=128, row=256B = 32 lanes x 8B; 2 items/step, 2-unroll
__global__ __launch_bounds__(256) void k_gather1(
    const ushort_t* __restrict__ t, ushort_t* __restrict__ outp,
    const int* __restrict__ rowptr, const int* __restrict__ csr, int n) {
  int wid = (blockIdx.x * blockDim.x + threadIdx.x) >> 6;
  int lane = threadIdx.x & 63;
  if (wid >= n) return;
  const int half = lane >> 5, sub = lane & 31;
  const int coff = sub * 4;
  int beg = rowptr[wid], end = rowptr[wid + 1];
  int nitems = end - beg + 1;
  float acc[4] = {};
  int i = 0;
  for (; i + 3 < nitems; i += 4) {
    int i0 = i + half, i1 = i + 2 + half;
    int r0 = (i0 == 0) ? wid : csr[beg + i0 - 1];
    int r1 = csr[beg + i1 - 1];
    u16x4 v0 = *reinterpret_cast<const u16x4*>(t + (size_t)r0 * IN_F + coff);
    u16x4 v1 = *reinterpret_cast<const u16x4*>(t + (size_t)r1 * IN_F + coff);
#pragma unroll
    for (int k = 0; k < 4; ++k) acc[k] += bf2f(v0[k]);
#pragma unroll
    for (int k = 0; k < 4; ++k) acc[k] += bf2f(v1[k]);
  }
  for (; i < nitems; i += 2) {
    int i0 = i + half;
    if (i0 < nitems) {
      int r0 = (i0 == 0) ? wid : csr[beg + i0 - 1];
      u16x4 v0 = *reinterpret_cast<const u16x4*>(t + (size_t)r0 * IN_F + coff);
#pragma unroll
      for (int k = 0; k < 4; ++k) acc[k] += bf2f(v0[k]);
    }
  }
#pragma unroll
  for (int k = 0; k < 4; ++k) acc[k] += __shfl_xor(acc[k], 32);
  if (half == 0) {
    u16x4 o;
#pragma unroll
    for (int k = 0; k < 4; ++k) o[k] = f2bf(acc[k]);
    *reinterpret_cast<u16x4*>(outp + (size_t)wid * IN_F + coff) = o;
  }
}

// layer 2: F=256, row=512B = 32 lanes x 16B; 2 items/step, 2-unroll
__global__ __launch_bounds__(256) void k_gather2(
    const ushort_t* __restrict__ t, ushort_t* __restrict__ outp,
    const int* __restrict__ rowptr, const int* __restrict__ csr,
    const float* __restrict__ dinv, const float* __restrict__ bias, int n) {
  int wid = (blockIdx.x * blockDim.x + threadIdx.x) >> 6;
  int lane = threadIdx.x & 63;
  if (wid >= n) return;
  const int half = lane >> 5, sub = lane & 31;
  const int coff = sub * 8;
  int beg = rowptr[wid], end = rowptr[wid + 1];
  int nitems = end - beg + 1;
  float acc[8] = {};
  int i = 0;
  for (; i + 3 < nitems; i += 4) {
    int i0 = i + half, i1 = i + 2 + half;
    int r0 = (i0 == 0) ? wid : csr[beg + i0 - 1];
    int r1 = csr[beg + i1 - 1];
    u16x8 v0 = *reinterpret_cast<const u16x8*>(t + (size_t)r0 * HID_F + coff);
    u16x8 v1 = *reinterpret_cast<const u16x8*>(t + (size_t)r1 * HID_F + coff);
#pragma unroll
    for (int k = 0; k < 8; ++k) acc[k] += bf2f(v0[k]);
#pragma unroll
    for (int k = 0; k < 8; ++k) acc[k] += bf2f(v1[k]);
  }
  for (; i < nitems; i += 2) {
    int i0 = i + half;
    if (i0 < nitems) {
      int r0 = (i0 == 0) ? wid : csr[beg + i0 - 1];
      u16x8 v0 = *reinterpret_cast<const u16x8*>(t + (size_t)r0 * HID_F + coff);
#pragma unroll
      for (int k = 0; k < 8; ++k) acc[k] += bf2f(v0[k]);
    }
  }
#pragma unroll
  for (int k = 0; k < 8; ++k) acc[k] += __shfl_xor(acc[k], 32);
  if (half == 0) {
    float s = dinv[wid];
    u16x8 o;
#pragma unroll
    for (int k = 0; k < 8; ++k) o[k] = f2bf(fmaxf(fmaf(acc[k], s, bias[coff + k]), 0.f));
    *reinterpret_cast<u16x8*>(outp + (size_t)wid * HID_F + coff) = o;
  }
}

// layer 3: F=64, row=128B = 16 lanes x 8B; 4 items/step; bias + L2-normalize
__global__ __launch_bounds__(256) void k_gather3(
    const ushort_t* __restrict__ t, float* __restrict__ outp,
    const int* __restrict__ rowptr, const int* __restrict__ csr,
    const float* __restrict__ dinv, const float* __restrict__ b3, int n) {
  int wid = (blockIdx.x * blockDim.x + threadIdx.x) >> 6;
  int lane = threadIdx.x & 63;
  if (wid >= n) return;
  const int q = lane >> 4, sub = lane & 15;
  const int coff = sub * 4;
  int beg = rowptr[wid], end = rowptr[wid + 1];
  int nitems = end - beg + 1;
  float acc[4] = {};
  for (int i = 0; i < nitems; i += 4) {
    int i0 = i + q;
    if (i0 < nitems) {
      int r0 = (i0 == 0) ? wid : csr[beg + i0 - 1];
      u16x4 v0 = *reinterpret_cast<const u16x4*>(t + (size_t)r0 * EMB_F + coff);
#pragma unroll
      for (int k = 0; k < 4; ++k) acc[k] += bf2f(v0[k]);
    }
  }
#pragma unroll
  for (int k = 0; k < 4; ++k) acc[k] += __shfl_xor(acc[k], 16);
#pragma unroll
  for (int k = 0; k < 4; ++k) acc[k] += __shfl_xor(acc[k], 32);
  float s = dinv[wid];
  float v[4], ss = 0.f;
#pragma unroll
  for (int k = 0; k < 4; ++k) {
    v[k] = fmaf(acc[k], s, b3[coff + k]);
    ss = fmaf(v[k], v[k], ss);
  }
#pragma unroll
  for (int off = 8; off > 0; off >>= 1) ss += __shfl_xor(ss, off);
  float inv = 1.0f / fmaxf(sqrtf(ss), 1e-12f);
  if (lane < 16) {
    float4 o = make_float4(v[0] * inv, v[1] * inv, v[2] * inv, v[3] * inv);
    *reinterpret_cast<float4*>(outp + (size_t)wid * EMB_F + coff) = o;
  }
}

// ---------------- LDS-free MFMA GEMM ----------------
// C[M][N] = dinv[row] * (A[M][K] @ Wt[N][K]^T)  (+bias, relu if RELU)
// wave-tile 64x64; mfma_f32_16x16x32_bf16; C/D: col=lane&15, row=(lane>>4)*4+reg

template<int K, bool RELU>
__global__ __launch_bounds__(256) void k_mfma_gemm(
    const ushort_t* __restrict__ A, const ushort_t* __restrict__ Wt,
    ushort_t* __restrict__ C,
    const float* __restrict__ dinv, const float* __restrict__ bias,
    int M, int NT /* N/64 */) {
  int w = blockIdx.x * 4 + (threadIdx.x >> 6);
  int lane = threadIdx.x & 63;
  int mt = w / NT, nt = w - mt * NT;
  int mbase = mt * 64, nbase = nt * 64;
  if (mbase >= M) return;
  const int lrow = lane & 15;
  const int lk = (lane >> 4) * 8;
  const int N = NT * 64;

  int rows[4];
#pragma unroll
  for (int i = 0; i < 4; ++i) {
    int r = mbase + i * 16 + lrow;
    rows[i] = (r < M) ? r : (M - 1);  // clamp loads; stores guarded
  }

  f32x4 acc[4][4] = {};

#pragma unroll 2
  for (int k0 = 0; k0 < K; k0 += 32) {
    bf16x8 a[4], b[4];
#pragma unroll
    for (int i = 0; i < 4; ++i)
      a[i] = *reinterpret_cast<const bf16x8*>(A + (size_t)rows[i] * K + k0 + lk);
#pragma unroll
    for (int n = 0; n < 4; ++n)
      b[n] = *reinterpret_cast<const bf16x8*>(Wt + (size_t)(nbase + n * 16 + lrow) * K + k0 + lk);
#pragma unroll
    for (int i = 0; i < 4; ++i)
#pragma unroll
      for (int n = 0; n < 4; ++n)
        acc[i][n] = __builtin_amdgcn_mfma_f32_16x16x32_bf16(a[i], b[n], acc[i][n], 0, 0, 0);
  }

#pragma unroll
  for (int i = 0; i < 4; ++i) {
    int growb = mbase + i * 16 + (lane >> 4) * 4;
#pragma unroll
    for (int r = 0; r < 4; ++r) {
      int grow = growb + r;
      if (grow >= M) continue;
      float s = dinv[grow];
#pragma unroll
      for (int n = 0; n < 4; ++n) {
        int gcol = nbase + n * 16 + (lane & 15);
        float v = acc[i][n][r] * s;
        if (RELU) v = fmaxf(v + bias[gcol], 0.f);
        C[(size_t)grow * N + gcol] = f2bf(v);
      }
    }
  }
}

// ---------------- launch ----------------

extern "C" void kernel_launch(void* const* d_in, const int* in_sizes, int n_in,
                              void* d_out, int out_size, void* d_ws, size_t ws_size,
                              hipStream_t stream) {
  const float* x  = (const float*)d_in[0];
  const int*   ei = (const int*)d_in[1];
  const float* W1 = (const float*)d_in[2];
  const float* b1 = (const float*)d_in[3];
  const float* W2 = (const float*)d_in[4];
  const float* b2 = (const float*)d_in[5];
  const float* W3 = (const float*)d_in[6];
  const float* b3 = (const float*)d_in[7];
  const int N = in_sizes[0] / IN_F;
  const int E = in_sizes[1] / 2;
  const int* src = ei;
  const int* dst = ei + E;

  char* m = (char*)d_ws;
  auto alloc = [&](size_t bytes) { char* p = m; m += (bytes + 255) & ~(size_t)255; return p; };
  ushort_t* U1  = (ushort_t*)alloc((size_t)N * HID_F * 2);  // N x 256 bf16
  ushort_t* U2  = (ushort_t*)alloc((size_t)N * HID_F * 2);
  ushort_t* W1t = (ushort_t*)alloc((size_t)IN_F * HID_F * 2);
  ushort_t* W2t = (ushort_t*)alloc((size_t)HID_F * HID_F * 2);
  ushort_t* W3t = (ushort_t*)alloc((size_t)HID_F * EMB_F * 2);
  float*    dinv    = (float*)alloc((size_t)N * 4);
  int*      rowptr  = (int*)alloc((size_t)(N + 1) * 4);
  int*      ghist   = (int*)alloc(NBKT * 4);
  int*      bstart  = (int*)alloc(NBKT * 4);
  int*      gcursor = (int*)alloc(NBKT * 4);
  unsigned* staged  = (unsigned*)alloc((size_t)E * 4);
  int*      csr     = (int*)alloc((size_t)E * 4);
  float*    out     = (float*)d_out;

  const int nb = (N + 255) / 256;        // buckets (<= NBKT)
  const int echunks = (E + CHUNK - 1) / CHUNK;
  constexpr int SETUP_W = IN_F * HID_F + HID_F * HID_F + HID_F * EMB_F + NBKT;

  // weights -> bf16 transposed; ghist = 0
  k_setup<<<(SETUP_W + 255) / 256, 256, 0, stream>>>(W1, W2, W3, W1t, W2t, W3t, ghist);

  // bucketed CSR build
  k_hist  <<<echunks, 512, 0, stream>>>(dst, ghist, E);
  k_bscan <<<1, NBKT, 0, stream>>>(ghist, bstart, gcursor);
  k_passA <<<echunks, 512, 0, stream>>>(src, dst, gcursor, staged, E);

  // fused: dinv + rowptr + csr placement + xb = bf16(x * dinv)   (xb aliased into U2)
  ushort_t* xb = U2;
  k_Bfused<<<nb, 256, 0, stream>>>(staged, bstart, ghist, x, dinv, rowptr, csr, xb, N, E);

  const int gblocks = (N + 3) / 4;  // 4 waves per block, 1 node per wave
  const int MT = (N + 63) / 64;

  // layer 1: gather xb -> aggX bf16 [N,128]; GEMM 128->256 (+dinv row, +b1, relu)
  ushort_t* aggX = U1;
  k_gather1<<<gblocks, 256, 0, stream>>>(xb, aggX, rowptr, csr, N);
  ushort_t* h1 = U2;
  k_mfma_gemm<IN_F, true><<<(MT * (HID_F / 64) + 3) / 4, 256, 0, stream>>>(
      aggX, W1t, h1, dinv, b1, N, HID_F / 64);

  // layer 2: GEMM 256->256 (dinv row) -> t2; gather (+dinv, b2, relu) -> h2
  ushort_t* t2 = U1;
  k_mfma_gemm<HID_F, false><<<(MT * (HID_F / 64) + 3) / 4, 256, 0, stream>>>(
      h1, W2t, t2, dinv, nullptr, N, HID_F / 64);
  ushort_t* h2 = U2;
  k_gather2<<<gblocks, 256, 0, stream>>>(t2, h2, rowptr, csr, dinv, b2, N);

  // layer 3: GEMM 256->64 (dinv row) -> t3; gather (+dinv, b3) + L2-normalize -> out
  ushort_t* t3 = U1;
  k_mfma_gemm<HID_F, false><<<(MT * (EMB_F / 64) + 3) / 4, 256, 0, stream>>>(
      h2, W3t, t3, dinv, nullptr, N, EMB_F / 64);
  k_gather3<<<gblocks, 256, 0, stream>>>(t3, out, rowptr, csr, dinv, b3, N);
}